// Round 5
// baseline (321.628 us; speedup 1.0000x reference)
//
#include <hip/hip_runtime.h>

typedef __attribute__((ext_vector_type(8))) short short8;
typedef __attribute__((ext_vector_type(4))) float f32x4;
typedef __attribute__((ext_vector_type(16))) float f32x16;
typedef unsigned short u16;
typedef unsigned int u32;

#define DEVFN static __device__ __forceinline__

DEVFN u16 f2b(float f) {
  u32 u = __builtin_bit_cast(u32, f);
  u32 r = u + 0x7fffu + ((u >> 16) & 1u);
  return (u16)(r >> 16);
}

DEVFN float b2f(u16 b) {
  u32 u = ((u32)b) << 16;
  return __builtin_bit_cast(float, u);
}

DEVFN short8 ldfrag(const void* p) {
  return __builtin_bit_cast(short8, *(const uint4*)p);
}

#define MFMA16(a, b, c) __builtin_amdgcn_mfma_f32_16x16x32_bf16((a), (b), (c), 0, 0, 0)
#define MFMA32(a, b, c) __builtin_amdgcn_mfma_f32_32x32x16_bf16((a), (b), (c), 0, 0, 0)
#define EXP2(x) __builtin_amdgcn_exp2f(x)

DEVFN void llds16(const void* g, void* l) {
  __builtin_amdgcn_global_load_lds((const __attribute__((address_space(1))) void*)g,
                                   (__attribute__((address_space(3))) void*)l, 16, 0, 0);
}

DEVFN float gelu_exact(float v) {
  return 0.5f * v * (1.0f + erff(v * 0.70710678118654752f));
}

// ---------------- merged f32 -> bf16 weight convert ----------------
__global__ void k_f2bm(const float* s0, const float* s1, const float* s2,
                       const float* s3, const float* s4, const float* s5,
                       u16* d0, u16* d1, u16* d2, u16* d3, u16* d4, u16* d5) {
  int i = blockIdx.x * 256 + threadIdx.x;
  const float* s;
  u16* d;
  int n4;
  switch (blockIdx.y) {
    case 0: s = s0; d = d0; n4 = 131072; break;
    case 1: s = s1; d = d1; n4 = 131072; break;
    case 2: s = s2; d = d2; n4 = 131072; break;
    case 3: s = s3; d = d3; n4 = 131072; break;
    case 4: s = s4; d = d4; n4 = 65536; break;
    default: s = s5; d = d5; n4 = 65536; break;
  }
  if (i >= n4) return;
  float4 v = ((const float4*)s)[i];
  ushort4 o = { f2b(v.x), f2b(v.y), f2b(v.z), f2b(v.w) };
  ((ushort4*)d)[i] = o;
}

// ---------------- LayerNorm (256 cols), f32 in -> bf16 out ----------------
__global__ __launch_bounds__(256) void k_ln(const float* __restrict__ x,
                                            const float* __restrict__ g,
                                            const float* __restrict__ b,
                                            u16* __restrict__ out) {
  int row = blockIdx.x * 4 + (threadIdx.x >> 6);
  int l = threadIdx.x & 63;
  const float4 v = *(const float4*)(x + (size_t)row * 256 + l * 4);
  float s = v.x + v.y + v.z + v.w;
#pragma unroll
  for (int m = 1; m < 64; m <<= 1) s += __shfl_xor(s, m);
  float mu = s * (1.0f / 256.0f);
  float dx = v.x - mu, dy = v.y - mu, dz = v.z - mu, dw = v.w - mu;
  float q = dx * dx + dy * dy + dz * dz + dw * dw;
#pragma unroll
  for (int m = 1; m < 64; m <<= 1) q += __shfl_xor(q, m);
  float r = rsqrtf(q * (1.0f / 256.0f) + 1e-5f);
  float4 gv = *(const float4*)(g + l * 4);
  float4 bv = *(const float4*)(b + l * 4);
  ushort4 o = { f2b(dx * r * gv.x + bv.x), f2b(dy * r * gv.y + bv.y),
                f2b(dz * r * gv.z + bv.z), f2b(dw * r * gv.w + bv.w) };
  *(ushort4*)(out + (size_t)row * 256 + l * 4) = o;
}

// ---------------- GEMM: C[M,N] = A[M,K] * B[N,K]^T, bf16 inputs ----------------
// EPI 3: bf16 + bias + GELU    EPI 4: f32 partial (split-K over gridDim.z)
template <int EPI>
__global__ __launch_bounds__(256, 2) void k_gemm(const u16* __restrict__ A,
                                                 const u16* __restrict__ B,
                                                 void* __restrict__ out,
                                                 const float* __restrict__ bias,
                                                 const float* __restrict__ resid,
                                                 int M, int N, int K) {
  __shared__ __attribute__((aligned(16))) u16 As[128 * 32];
  __shared__ __attribute__((aligned(16))) u16 Bs[128 * 32];
  const int t = threadIdx.x;
  const int w = t >> 6, l = t & 63, g = l >> 4, c = l & 15;
  const int wr = w >> 1, wc = w & 1;
  const int bm = blockIdx.y, bn = blockIdx.x;

  f32x4 acc[4][4] = {};
  int nk = K >> 5, kk0 = 0;
  if (EPI == 4) { nk = nk / gridDim.z; kk0 = blockIdx.z * nk; }

  const int srow = t >> 2;
  const int sj = t & 3;
  const char* Abase = (const char*)A;
  const char* Bbase = (const char*)B;

  for (int kk = kk0; kk < kk0 + nk; ++kk) {
    const size_t kb = (size_t)kk * 64;
    uint4 a0 = *(const uint4*)(Abase + ((size_t)(bm * 128 + srow) * K) * 2 + kb + sj * 16);
    uint4 a1 = *(const uint4*)(Abase + ((size_t)(bm * 128 + srow + 64) * K) * 2 + kb + sj * 16);
    uint4 b0 = *(const uint4*)(Bbase + ((size_t)(bn * 128 + srow) * K) * 2 + kb + sj * 16);
    uint4 b1 = *(const uint4*)(Bbase + ((size_t)(bn * 128 + srow + 64) * K) * 2 + kb + sj * 16);
    __syncthreads();
    const int sw0 = (sj * 16) ^ (((srow >> 1) & 3) << 4);
    const int sw1 = (sj * 16) ^ ((((srow + 64) >> 1) & 3) << 4);
    *(uint4*)((char*)As + srow * 64 + sw0) = a0;
    *(uint4*)((char*)As + (srow + 64) * 64 + sw1) = a1;
    *(uint4*)((char*)Bs + srow * 64 + sw0) = b0;
    *(uint4*)((char*)Bs + (srow + 64) * 64 + sw1) = b1;
    __syncthreads();
    short8 af[4], bfr[4];
#pragma unroll
    for (int m = 0; m < 4; ++m) {
      int row = wr * 64 + m * 16 + c;
      af[m] = ldfrag((const char*)As + row * 64 + ((g * 16) ^ (((row >> 1) & 3) << 4)));
    }
#pragma unroll
    for (int n = 0; n < 4; ++n) {
      int row = wc * 64 + n * 16 + c;
      bfr[n] = ldfrag((const char*)Bs + row * 64 + ((g * 16) ^ (((row >> 1) & 3) << 4)));
    }
#pragma unroll
    for (int m = 0; m < 4; ++m)
#pragma unroll
      for (int n = 0; n < 4; ++n) acc[m][n] = MFMA16(af[m], bfr[n], acc[m][n]);
  }

  const int row0 = bm * 128 + wr * 64 + 4 * g;
  const int col0 = bn * 128 + wc * 64 + c;
#pragma unroll
  for (int m = 0; m < 4; ++m) {
#pragma unroll
    for (int n = 0; n < 4; ++n) {
      const int row = row0 + m * 16;
      const int col = col0 + n * 16;
      if (EPI == 3) {
        float bc = bias[col];
#pragma unroll
        for (int rr = 0; rr < 4; ++rr)
          ((u16*)out)[(size_t)(row + rr) * N + col] = f2b(gelu_exact(acc[m][n][rr] + bc));
      } else {
        float* po = (float*)out + (size_t)blockIdx.z * M * N;
#pragma unroll
        for (int rr = 0; rr < 4; ++rr)
          po[(size_t)(row + rr) * N + col] = acc[m][n][rr];
      }
    }
  }
}

// ---------------- merged QKV GEMM: 3 outputs, shared A; sel 2 stores transposed ----------------
__global__ __launch_bounds__(256, 2) void k_gemm_qkv(const u16* __restrict__ A,
                                                     const u16* __restrict__ Bq,
                                                     const u16* __restrict__ Bk,
                                                     const u16* __restrict__ Bv,
                                                     u16* __restrict__ Oq,
                                                     u16* __restrict__ Ok,
                                                     u16* __restrict__ Ov) {
  constexpr int M = 4096, N = 2048, K = 256;
  __shared__ __attribute__((aligned(16))) u16 As[128 * 32];
  __shared__ __attribute__((aligned(16))) u16 Bs[128 * 32];
  const int t = threadIdx.x;
  const int w = t >> 6, l = t & 63, g = l >> 4, c = l & 15;
  const int wr = w >> 1, wc = w & 1;
  const int sel = blockIdx.x >> 4;
  const int bn = blockIdx.x & 15;
  const int bm = blockIdx.y;
  const u16* B = sel == 0 ? Bq : (sel == 1 ? Bk : Bv);

  f32x4 acc[4][4] = {};
  const int srow = t >> 2;
  const int sj = t & 3;
  const char* Abase = (const char*)A;
  const char* Bbase = (const char*)B;

  for (int kk = 0; kk < 8; ++kk) {
    const size_t kb = (size_t)kk * 64;
    uint4 a0 = *(const uint4*)(Abase + ((size_t)(bm * 128 + srow) * K) * 2 + kb + sj * 16);
    uint4 a1 = *(const uint4*)(Abase + ((size_t)(bm * 128 + srow + 64) * K) * 2 + kb + sj * 16);
    uint4 b0 = *(const uint4*)(Bbase + ((size_t)(bn * 128 + srow) * K) * 2 + kb + sj * 16);
    uint4 b1 = *(const uint4*)(Bbase + ((size_t)(bn * 128 + srow + 64) * K) * 2 + kb + sj * 16);
    __syncthreads();
    const int sw0 = (sj * 16) ^ (((srow >> 1) & 3) << 4);
    const int sw1 = (sj * 16) ^ ((((srow + 64) >> 1) & 3) << 4);
    *(uint4*)((char*)As + srow * 64 + sw0) = a0;
    *(uint4*)((char*)As + (srow + 64) * 64 + sw1) = a1;
    *(uint4*)((char*)Bs + srow * 64 + sw0) = b0;
    *(uint4*)((char*)Bs + (srow + 64) * 64 + sw1) = b1;
    __syncthreads();
    short8 af[4], bfr[4];
#pragma unroll
    for (int m = 0; m < 4; ++m) {
      int row = wr * 64 + m * 16 + c;
      af[m] = ldfrag((const char*)As + row * 64 + ((g * 16) ^ (((row >> 1) & 3) << 4)));
    }
#pragma unroll
    for (int n = 0; n < 4; ++n) {
      int row = wc * 64 + n * 16 + c;
      bfr[n] = ldfrag((const char*)Bs + row * 64 + ((g * 16) ^ (((row >> 1) & 3) << 4)));
    }
#pragma unroll
    for (int m = 0; m < 4; ++m)
#pragma unroll
      for (int n = 0; n < 4; ++n) acc[m][n] = MFMA16(af[m], bfr[n], acc[m][n]);
  }

  const int row0 = bm * 128 + wr * 64 + 4 * g;
  const int col0 = bn * 128 + wc * 64 + c;
  if (sel < 2) {
    u16* out = sel ? Ok : Oq;
#pragma unroll
    for (int m = 0; m < 4; ++m)
#pragma unroll
      for (int n = 0; n < 4; ++n)
#pragma unroll
        for (int rr = 0; rr < 4; ++rr)
          out[(size_t)(row0 + m * 16 + rr) * N + col0 + n * 16] = f2b(acc[m][n][rr]);
  } else {
#pragma unroll
    for (int m = 0; m < 4; ++m)
#pragma unroll
      for (int n = 0; n < 4; ++n) {
        ushort4 o = { f2b(acc[m][n][0]), f2b(acc[m][n][1]), f2b(acc[m][n][2]), f2b(acc[m][n][3]) };
        *(ushort4*)(Ov + (size_t)(col0 + n * 16) * M + row0 + m * 16) = o;
      }
  }
}

// ---------------- reduce 4 split-K partials + bias + residual -> f32 ----------------
__global__ __launch_bounds__(256) void k_red4(const float* __restrict__ p,
                                              const float* __restrict__ bias,
                                              const float* __restrict__ resid,
                                              float* __restrict__ out) {
  int i = blockIdx.x * 256 + threadIdx.x;
  const float4* p4 = (const float4*)p;
  float4 a = p4[i], b = p4[i + 262144], c = p4[i + 524288], d = p4[i + 786432];
  float4 r = ((const float4*)resid)[i];
  float4 bb = ((const float4*)bias)[i & 63];
  float4 o;
  o.x = a.x + b.x + c.x + d.x + r.x + bb.x;
  o.y = a.y + b.y + c.y + d.y + r.y + bb.y;
  o.z = a.z + b.z + c.z + d.z + r.z + bb.z;
  o.w = a.w + b.w + c.w + d.w + r.w + bb.w;
  ((float4*)out)[i] = o;
}

// ---------------- fused: reduce 4 split-K partials + bias + resid -> x2, then LN -> bf16 ----------------
__global__ __launch_bounds__(256) void k_red4ln(const float* __restrict__ p,
                                                const float* __restrict__ bias,
                                                const float* __restrict__ resid,
                                                const float* __restrict__ g,
                                                const float* __restrict__ b,
                                                float* __restrict__ x2,
                                                u16* __restrict__ out) {
  int row = blockIdx.x * 4 + (threadIdx.x >> 6);
  int l = threadIdx.x & 63;
  int i = row * 64 + l;
  const float4* p4 = (const float4*)p;
  float4 a = p4[i], bq = p4[i + 262144], cq = p4[i + 524288], dq = p4[i + 786432];
  float4 r = ((const float4*)resid)[i];
  float4 bi = ((const float4*)bias)[l];
  float4 v;
  v.x = a.x + bq.x + cq.x + dq.x + r.x + bi.x;
  v.y = a.y + bq.y + cq.y + dq.y + r.y + bi.y;
  v.z = a.z + bq.z + cq.z + dq.z + r.z + bi.z;
  v.w = a.w + bq.w + cq.w + dq.w + r.w + bi.w;
  ((float4*)x2)[i] = v;
  float s = v.x + v.y + v.z + v.w;
#pragma unroll
  for (int m = 1; m < 64; m <<= 1) s += __shfl_xor(s, m);
  float mu = s * (1.0f / 256.0f);
  float dx = v.x - mu, dy = v.y - mu, dz = v.z - mu, dw = v.w - mu;
  float q = dx * dx + dy * dy + dz * dz + dw * dw;
#pragma unroll
  for (int m = 1; m < 64; m <<= 1) q += __shfl_xor(q, m);
  float rr = rsqrtf(q * (1.0f / 256.0f) + 1e-5f);
  float4 gv = *(const float4*)(g + l * 4);
  float4 bv = *(const float4*)(b + l * 4);
  ushort4 o = { f2b(dx * rr * gv.x + bv.x), f2b(dy * rr * gv.y + bv.y),
                f2b(dz * rr * gv.z + bv.z), f2b(dw * rr * gv.w + bv.w) };
  *(ushort4*)(out + (size_t)row * 256 + l * 4) = o;
}

// ---------------- Flash attention (kv-split-3): 8 heads, d_head=256, N=4096 ----------------
// 32x32x16 MFMA, swapped QK^T (A=K,B=Q), 4 waves x 32 q, KVBLK=32.
// LDS 48KB: K dbuf 2x16KB + V single 16KB -> 3 blocks/CU. In-register P. 1D grid, head=lin&7.
__global__ __launch_bounds__(256) void k_attn(const u16* __restrict__ Q,
                                              const u16* __restrict__ Km,
                                              const u16* __restrict__ VT,
                                              u16* __restrict__ part,
                                              float* __restrict__ ml) {
  __shared__ __attribute__((aligned(16))) char smem[49152];
  const int t = threadIdx.x;
  const int w = t >> 6, l = t & 63;
  const int q31 = l & 31, hi = l >> 5;
  const int lin = blockIdx.x;
  const int head = lin & 7, qb = (lin >> 3) & 31, sp = lin >> 8;
  const int kvbase = sp * 1376;
  const int nr = (sp == 2) ? 42 : 43;
  const float C2 = 0.0625f * 1.44269504f;  // 1/sqrt(256) * log2(e)

  short8 qf[16];
  {
    const char* qp = (const char*)Q + (size_t)(qb * 128 + w * 32 + q31) * 4096 + head * 512 + hi * 16;
#pragma unroll
    for (int ks = 0; ks < 16; ++ks) qf[ks] = ldfrag(qp + ks * 32);
  }

  f32x16 o[8] = {};
  float m = -1e30f, lsum = 0.0f;

  const char* KbaseH = (const char*)Km + head * 512;
  const char* VbaseH = (const char*)VT + (size_t)head * 256 * 8192;

  auto stageK = [&](int c) {
    char* kd = smem + (c & 1) * 16384;
    const int kv0 = kvbase + c * 32;
#pragma unroll
    for (int ii = 0; ii < 4; ++ii) {
      const int row = w * 8 + ii * 2 + hi;
      llds16(KbaseH + (size_t)(kv0 + row) * 4096 + ((q31 ^ row) << 4), kd + (w * 4 + ii) * 1024);
    }
  };
  auto stageV = [&](int c) {
    char* vd = smem + 32768;
    const int kv0 = kvbase + c * 32;
#pragma unroll
    for (int ii = 0; ii < 4; ++ii) {
      const int row = w * 64 + ii * 16 + (l >> 2);
      llds16(VbaseH + (size_t)row * 8192 + (size_t)kv0 * 2 + (((l & 3) ^ ((row >> 3) & 3)) << 4),
             vd + (w * 4 + ii) * 1024);
    }
  };

  stageK(0);
  stageV(0);
  for (int c = 0; c < nr; ++c) {
    asm volatile("s_waitcnt vmcnt(0)" ::: "memory");
    __builtin_amdgcn_s_barrier();
    __builtin_amdgcn_sched_barrier(0);
    if (c < nr - 1) stageK(c + 1);

    const char* kd = smem + (c & 1) * 16384;
    const char* vd = smem + 32768;

    // S^T = K . Q^T : C[kv][q], 2 independent accumulator chains
    f32x16 sA = {}, sB = {};
    const char* ka = kd + q31 * 512;
    const int sswz = q31 << 4;
    __builtin_amdgcn_s_setprio(1);
#pragma unroll
    for (int ks = 0; ks < 16; ks += 2) {
      short8 a0 = ldfrag(ka + ((ks * 32 + hi * 16) ^ sswz));
      short8 a1 = ldfrag(ka + (((ks + 1) * 32 + hi * 16) ^ sswz));
      sA = MFMA32(a0, qf[ks], sA);
      sB = MFMA32(a1, qf[ks + 1], sB);
    }
    __builtin_amdgcn_s_setprio(0);
    f32x16 s = sA + sB;

    // online softmax (kv lane-local), tree reductions, defer-max
    float m8[8];
#pragma unroll
    for (int i = 0; i < 8; ++i) m8[i] = fmaxf(s[i], s[i + 8]);
#pragma unroll
    for (int i = 0; i < 4; ++i) m8[i] = fmaxf(m8[i], m8[i + 4]);
    float pm = fmaxf(fmaxf(m8[0], m8[1]), fmaxf(m8[2], m8[3]));
    pm = fmaxf(pm, __shfl_xor(pm, 32));
    if (__any(pm > m + 64.0f)) {
      float mn = fmaxf(m, pm);
      float sc = EXP2((m - mn) * C2);
      m = mn;
      lsum *= sc;
#pragma unroll
      for (int i = 0; i < 16; ++i) {
        const int r = (i & 3) + 8 * (i >> 2) + 4 * hi;
        float sclr = __shfl(sc, r);
#pragma unroll
        for (int dt = 0; dt < 8; ++dt) o[dt][i] *= sclr;
      }
    }
    const float mc2 = m * C2;
    float p[16];
#pragma unroll
    for (int i = 0; i < 16; ++i) p[i] = EXP2(fmaf(s[i], C2, -mc2));
    float r8[8];
#pragma unroll
    for (int i = 0; i < 8; ++i) r8[i] = p[i] + p[i + 8];
#pragma unroll
    for (int i = 0; i < 4; ++i) r8[i] += r8[i + 4];
    float rs = (r8[0] + r8[1]) + (r8[2] + r8[3]);
    rs += __shfl_xor(rs, 32);
    lsum += rs;

    // in-register P -> A-fragments (q = lane&31; redistribute kv via permlane32_swap)
    u32 pk[8];
#pragma unroll
    for (int j = 0; j < 8; ++j)
      asm("v_cvt_pk_bf16_f32 %0, %1, %2" : "=v"(pk[j]) : "v"(p[2 * j]), "v"(p[2 * j + 1]));
    asm("v_permlane32_swap_b32 %0, %1" : "+v"(pk[0]), "+v"(pk[2]));
    asm("v_permlane32_swap_b32 %0, %1" : "+v"(pk[1]), "+v"(pk[3]));
    asm("v_permlane32_swap_b32 %0, %1" : "+v"(pk[4]), "+v"(pk[6]));
    asm("v_permlane32_swap_b32 %0, %1" : "+v"(pk[5]), "+v"(pk[7]));
    uint4 f0 = { pk[0], pk[1], pk[2], pk[3] };
    uint4 f1 = { pk[4], pk[5], pk[6], pk[7] };
    short8 pa0 = __builtin_bit_cast(short8, f0);
    short8 pa1 = __builtin_bit_cast(short8, f1);

    // O += P . V : B=V[kv][32d] from LDS, A=P in regs
    __builtin_amdgcn_s_setprio(1);
#pragma unroll
    for (int dt = 0; dt < 8; ++dt) {
      const int row = dt * 32 + q31;
      const char* vr = vd + row * 64;
      const int vs = ((row >> 3) & 3) << 4;
      short8 b0 = ldfrag(vr + ((hi * 16) ^ vs));
      short8 b1 = ldfrag(vr + ((32 + hi * 16) ^ vs));
      o[dt] = MFMA32(pa0, b0, o[dt]);
      o[dt] = MFMA32(pa1, b1, o[dt]);
    }
    __builtin_amdgcn_s_setprio(0);
    __builtin_amdgcn_s_barrier();   // all waves done reading V(c)
    if (c < nr - 1) stageV(c + 1);
  }

  // epilogue: unnormalized bf16 partial + (m, l)
  u16* pb = part + (size_t)sp * 4096 * 2048;
#pragma unroll
  for (int i = 0; i < 16; ++i) {
    const int r = (i & 3) + 8 * (i >> 2) + 4 * hi;
    const size_t qg = (size_t)(qb * 128 + w * 32 + r);
#pragma unroll
    for (int dt = 0; dt < 8; ++dt)
      pb[qg * 2048 + head * 256 + dt * 32 + q31] = f2b(o[dt][i]);
  }
  if (hi == 0) {
    const int qg = qb * 128 + w * 32 + q31;
    ml[((sp * 2 + 0) * 8 + head) * 4096 + qg] = m;
    ml[((sp * 2 + 1) * 8 + head) * 4096 + qg] = lsum;
  }
}

// ---------------- merge 3 kv-split partials ----------------
__global__ __launch_bounds__(256) void k_merge3(const u16* __restrict__ part,
                                                const float* __restrict__ ml,
                                                u16* __restrict__ outp) {
  const int row = blockIdx.x;       // 4096
  const int t = threadIdx.x;        // 8 cols each
  const int c0 = t * 8;
  const int head = t >> 5;
  const float C2 = 0.0625f * 1.44269504f;
  float m0 = ml[(0 + head) * 4096 + row],  l0 = ml[(8 + head) * 4096 + row];
  float m1 = ml[(16 + head) * 4096 + row], l1 = ml[(24 + head) * 4096 + row];
  float m2 = ml[(32 + head) * 4096 + row], l2 = ml[(40 + head) * 4096 + row];
  float M = fmaxf(fmaxf(m0, m1), m2);
  float w0 = EXP2((m0 - M) * C2), w1 = EXP2((m1 - M) * C2), w2 = EXP2((m2 - M) * C2);
  float inv = 1.0f / (l0 * w0 + l1 * w1 + l2 * w2);
  w0 *= inv;
  w1 *= inv;
  w2 *= inv;
  const size_t base = (size_t)row * 2048 + c0;
  uint4 a = *(const uint4*)(part + base);
  uint4 b = *(const uint4*)(part + (size_t)4096 * 2048 + base);
  uint4 cc = *(const uint4*)(part + (size_t)2 * 4096 * 2048 + base);
  const u16* ah = (const u16*)&a;
  const u16* bh = (const u16*)&b;
  const u16* ch = (const u16*)&cc;
  ushort4 o0, o1;
  u16* oh0 = (u16*)&o0;
  u16* oh1 = (u16*)&o1;
#pragma unroll
  for (int j = 0; j < 4; ++j) {
    oh0[j] = f2b(b2f(ah[j]) * w0 + b2f(bh[j]) * w1 + b2f(ch[j]) * w2);
    oh1[j] = f2b(b2f(ah[j + 4]) * w0 + b2f(bh[j + 4]) * w1 + b2f(ch[j + 4]) * w2);
  }
  *(ushort4*)(outp + base) = o0;
  *(ushort4*)(outp + base + 4) = o1;
}

// ---------------- launch ----------------
extern "C" void kernel_launch(void* const* d_in, const int* in_sizes, int n_in,
                              void* d_out, int out_size, void* d_ws, size_t ws_size,
                              hipStream_t stream) {
  const float* x   = (const float*)d_in[0];
  const float* Wq  = (const float*)d_in[1];
  const float* Wk  = (const float*)d_in[2];
  const float* Wv  = (const float*)d_in[3];
  const float* Wo  = (const float*)d_in[4];
  const float* bo  = (const float*)d_in[5];
  const float* g1  = (const float*)d_in[6];
  const float* be1 = (const float*)d_in[7];
  const float* g2  = (const float*)d_in[8];
  const float* be2 = (const float*)d_in[9];
  const float* W1  = (const float*)d_in[10];
  const float* b1  = (const float*)d_in[11];
  const float* W2  = (const float*)d_in[12];
  const float* b2  = (const float*)d_in[13];

  char* ws = (char*)d_ws;
  size_t off = 0;
  auto alloc = [&](size_t n) {
    char* p = ws + off;
    off = (off + n + 255) & ~(size_t)255;
    return p;
  };
  u16* hb    = (u16*)alloc(4096 * 256 * 2);
  u16* Wqb   = (u16*)alloc(2048 * 256 * 2);
  u16* Wkb   = (u16*)alloc(2048 * 256 * 2);
  u16* Wvb   = (u16*)alloc(2048 * 256 * 2);
  u16* Wob   = (u16*)alloc(256 * 2048 * 2);
  u16* W1b   = (u16*)alloc(1024 * 256 * 2);
  u16* W2b   = (u16*)alloc(256 * 1024 * 2);
  u16* Qb    = (u16*)alloc((size_t)4096 * 2048 * 2);
  u16* Kb    = (u16*)alloc((size_t)4096 * 2048 * 2);
  u16* VTb   = (u16*)alloc((size_t)2048 * 4096 * 2);
  u16* attnb = (u16*)alloc((size_t)3 * 4096 * 2048 * 2);  // 3 kv-split partials; merged into slot 0
  float* mlb = (float*)alloc(48 * 4096 * 4);
  float* x2  = (float*)alloc(4096 * 256 * 4);
  u16* h2b   = (u16*)alloc(4096 * 256 * 2);
  u16* ffn1  = (u16*)alloc((size_t)4096 * 1024 * 2);
  float* pbuf = (float*)Qb;  // 16MB, dead after k_attn: 4x [4096][256] f32 split-K partials

  k_f2bm<<<dim3(512, 6), 256, 0, stream>>>(Wq, Wk, Wv, Wo, W1, W2, Wqb, Wkb, Wvb, Wob, W1b, W2b);

  k_ln<<<1024, 256, 0, stream>>>(x, g1, be1, hb);

  k_gemm_qkv<<<dim3(48, 32), 256, 0, stream>>>(hb, Wqb, Wkb, Wvb, Qb, Kb, VTb);

  k_attn<<<768, 256, 0, stream>>>(Qb, Kb, VTb, attnb, mlb);
  k_merge3<<<4096, 256, 0, stream>>>(attnb, mlb, attnb);

  k_gemm<4><<<dim3(2, 32, 4), 256, 0, stream>>>(attnb, Wob, pbuf, nullptr, nullptr, 4096, 256, 2048);
  k_red4ln<<<1024, 256, 0, stream>>>(pbuf, bo, x, g2, be2, x2, h2b);
  k_gemm<3><<<dim3(8, 32), 256, 0, stream>>>(h2b, W1b, ffn1, b1, nullptr, 4096, 1024, 256);
  k_gemm<4><<<dim3(2, 32, 4), 256, 0, stream>>>(ffn1, W2b, pbuf, nullptr, nullptr, 4096, 256, 1024);
  k_red4<<<1024, 256, 0, stream>>>(pbuf, b2, x2, (float*)d_out);
}

// Round 6
// 270.849 us; speedup vs baseline: 1.1875x; 1.1875x over previous
//
#include <hip/hip_runtime.h>

typedef __attribute__((ext_vector_type(8))) short short8;
typedef __attribute__((ext_vector_type(4))) float f32x4;
typedef __attribute__((ext_vector_type(16))) float f32x16;
typedef unsigned short u16;
typedef unsigned int u32;

#define DEVFN static __device__ __forceinline__

DEVFN u16 f2b(float f) {
  u32 u = __builtin_bit_cast(u32, f);
  u32 r = u + 0x7fffu + ((u >> 16) & 1u);
  return (u16)(r >> 16);
}

DEVFN float b2f(u16 b) {
  u32 u = ((u32)b) << 16;
  return __builtin_bit_cast(float, u);
}

DEVFN short8 ldfrag(const void* p) {
  return __builtin_bit_cast(short8, *(const uint4*)p);
}

#define MFMA16(a, b, c) __builtin_amdgcn_mfma_f32_16x16x32_bf16((a), (b), (c), 0, 0, 0)
#define MFMA32(a, b, c) __builtin_amdgcn_mfma_f32_32x32x16_bf16((a), (b), (c), 0, 0, 0)
#define EXP2(x) __builtin_amdgcn_exp2f(x)

DEVFN void llds16(const void* g, void* l) {
  __builtin_amdgcn_global_load_lds((const __attribute__((address_space(1))) void*)g,
                                   (__attribute__((address_space(3))) void*)l, 16, 0, 0);
}

DEVFN float gelu_exact(float v) {
  return 0.5f * v * (1.0f + erff(v * 0.70710678118654752f));
}

// ---------------- merged f32 -> bf16 weight convert ----------------
__global__ void k_f2bm(const float* s0, const float* s1, const float* s2,
                       const float* s3, const float* s4, const float* s5,
                       u16* d0, u16* d1, u16* d2, u16* d3, u16* d4, u16* d5) {
  int i = blockIdx.x * 256 + threadIdx.x;
  const float* s;
  u16* d;
  int n4;
  switch (blockIdx.y) {
    case 0: s = s0; d = d0; n4 = 131072; break;
    case 1: s = s1; d = d1; n4 = 131072; break;
    case 2: s = s2; d = d2; n4 = 131072; break;
    case 3: s = s3; d = d3; n4 = 131072; break;
    case 4: s = s4; d = d4; n4 = 65536; break;
    default: s = s5; d = d5; n4 = 65536; break;
  }
  if (i >= n4) return;
  float4 v = ((const float4*)s)[i];
  ushort4 o = { f2b(v.x), f2b(v.y), f2b(v.z), f2b(v.w) };
  ((ushort4*)d)[i] = o;
}

// ---------------- LayerNorm (256 cols), f32 in -> bf16 out ----------------
__global__ __launch_bounds__(256) void k_ln(const float* __restrict__ x,
                                            const float* __restrict__ g,
                                            const float* __restrict__ b,
                                            u16* __restrict__ out) {
  int row = blockIdx.x * 4 + (threadIdx.x >> 6);
  int l = threadIdx.x & 63;
  const float4 v = *(const float4*)(x + (size_t)row * 256 + l * 4);
  float s = v.x + v.y + v.z + v.w;
#pragma unroll
  for (int m = 1; m < 64; m <<= 1) s += __shfl_xor(s, m);
  float mu = s * (1.0f / 256.0f);
  float dx = v.x - mu, dy = v.y - mu, dz = v.z - mu, dw = v.w - mu;
  float q = dx * dx + dy * dy + dz * dz + dw * dw;
#pragma unroll
  for (int m = 1; m < 64; m <<= 1) q += __shfl_xor(q, m);
  float r = rsqrtf(q * (1.0f / 256.0f) + 1e-5f);
  float4 gv = *(const float4*)(g + l * 4);
  float4 bv = *(const float4*)(b + l * 4);
  ushort4 o = { f2b(dx * r * gv.x + bv.x), f2b(dy * r * gv.y + bv.y),
                f2b(dz * r * gv.z + bv.z), f2b(dw * r * gv.w + bv.w) };
  *(ushort4*)(out + (size_t)row * 256 + l * 4) = o;
}

// ---------------- GEMM: C[M,N] = A[M,K] * B[N,K]^T, bf16 inputs ----------------
// EPI 3: bf16 + bias + GELU    EPI 4: f32 partial (split-K over gridDim.z)
template <int EPI>
__global__ __launch_bounds__(256, 2) void k_gemm(const u16* __restrict__ A,
                                                 const u16* __restrict__ B,
                                                 void* __restrict__ out,
                                                 const float* __restrict__ bias,
                                                 const float* __restrict__ resid,
                                                 int M, int N, int K) {
  __shared__ __attribute__((aligned(16))) u16 As[128 * 32];
  __shared__ __attribute__((aligned(16))) u16 Bs[128 * 32];
  const int t = threadIdx.x;
  const int w = t >> 6, l = t & 63, g = l >> 4, c = l & 15;
  const int wr = w >> 1, wc = w & 1;
  const int bm = blockIdx.y, bn = blockIdx.x;

  f32x4 acc[4][4] = {};
  int nk = K >> 5, kk0 = 0;
  if (EPI == 4) { nk = nk / gridDim.z; kk0 = blockIdx.z * nk; }

  const int srow = t >> 2;
  const int sj = t & 3;
  const char* Abase = (const char*)A;
  const char* Bbase = (const char*)B;

  for (int kk = kk0; kk < kk0 + nk; ++kk) {
    const size_t kb = (size_t)kk * 64;
    uint4 a0 = *(const uint4*)(Abase + ((size_t)(bm * 128 + srow) * K) * 2 + kb + sj * 16);
    uint4 a1 = *(const uint4*)(Abase + ((size_t)(bm * 128 + srow + 64) * K) * 2 + kb + sj * 16);
    uint4 b0 = *(const uint4*)(Bbase + ((size_t)(bn * 128 + srow) * K) * 2 + kb + sj * 16);
    uint4 b1 = *(const uint4*)(Bbase + ((size_t)(bn * 128 + srow + 64) * K) * 2 + kb + sj * 16);
    __syncthreads();
    const int sw0 = (sj * 16) ^ (((srow >> 1) & 3) << 4);
    const int sw1 = (sj * 16) ^ ((((srow + 64) >> 1) & 3) << 4);
    *(uint4*)((char*)As + srow * 64 + sw0) = a0;
    *(uint4*)((char*)As + (srow + 64) * 64 + sw1) = a1;
    *(uint4*)((char*)Bs + srow * 64 + sw0) = b0;
    *(uint4*)((char*)Bs + (srow + 64) * 64 + sw1) = b1;
    __syncthreads();
    short8 af[4], bfr[4];
#pragma unroll
    for (int m = 0; m < 4; ++m) {
      int row = wr * 64 + m * 16 + c;
      af[m] = ldfrag((const char*)As + row * 64 + ((g * 16) ^ (((row >> 1) & 3) << 4)));
    }
#pragma unroll
    for (int n = 0; n < 4; ++n) {
      int row = wc * 64 + n * 16 + c;
      bfr[n] = ldfrag((const char*)Bs + row * 64 + ((g * 16) ^ (((row >> 1) & 3) << 4)));
    }
#pragma unroll
    for (int m = 0; m < 4; ++m)
#pragma unroll
      for (int n = 0; n < 4; ++n) acc[m][n] = MFMA16(af[m], bfr[n], acc[m][n]);
  }

  const int row0 = bm * 128 + wr * 64 + 4 * g;
  const int col0 = bn * 128 + wc * 64 + c;
#pragma unroll
  for (int m = 0; m < 4; ++m) {
#pragma unroll
    for (int n = 0; n < 4; ++n) {
      const int row = row0 + m * 16;
      const int col = col0 + n * 16;
      if (EPI == 3) {
        float bc = bias[col];
#pragma unroll
        for (int rr = 0; rr < 4; ++rr)
          ((u16*)out)[(size_t)(row + rr) * N + col] = f2b(gelu_exact(acc[m][n][rr] + bc));
      } else {
        float* po = (float*)out + (size_t)blockIdx.z * M * N;
#pragma unroll
        for (int rr = 0; rr < 4; ++rr)
          po[(size_t)(row + rr) * N + col] = acc[m][n][rr];
      }
    }
  }
}

// ---------------- merged QKV GEMM: 3 outputs, shared A; sel 2 stores transposed ----------------
__global__ __launch_bounds__(256, 2) void k_gemm_qkv(const u16* __restrict__ A,
                                                     const u16* __restrict__ Bq,
                                                     const u16* __restrict__ Bk,
                                                     const u16* __restrict__ Bv,
                                                     u16* __restrict__ Oq,
                                                     u16* __restrict__ Ok,
                                                     u16* __restrict__ Ov) {
  constexpr int M = 4096, N = 2048, K = 256;
  __shared__ __attribute__((aligned(16))) u16 As[128 * 32];
  __shared__ __attribute__((aligned(16))) u16 Bs[128 * 32];
  const int t = threadIdx.x;
  const int w = t >> 6, l = t & 63, g = l >> 4, c = l & 15;
  const int wr = w >> 1, wc = w & 1;
  const int sel = blockIdx.x >> 4;
  const int bn = blockIdx.x & 15;
  const int bm = blockIdx.y;
  const u16* B = sel == 0 ? Bq : (sel == 1 ? Bk : Bv);

  f32x4 acc[4][4] = {};
  const int srow = t >> 2;
  const int sj = t & 3;
  const char* Abase = (const char*)A;
  const char* Bbase = (const char*)B;

  for (int kk = 0; kk < 8; ++kk) {
    const size_t kb = (size_t)kk * 64;
    uint4 a0 = *(const uint4*)(Abase + ((size_t)(bm * 128 + srow) * K) * 2 + kb + sj * 16);
    uint4 a1 = *(const uint4*)(Abase + ((size_t)(bm * 128 + srow + 64) * K) * 2 + kb + sj * 16);
    uint4 b0 = *(const uint4*)(Bbase + ((size_t)(bn * 128 + srow) * K) * 2 + kb + sj * 16);
    uint4 b1 = *(const uint4*)(Bbase + ((size_t)(bn * 128 + srow + 64) * K) * 2 + kb + sj * 16);
    __syncthreads();
    const int sw0 = (sj * 16) ^ (((srow >> 1) & 3) << 4);
    const int sw1 = (sj * 16) ^ ((((srow + 64) >> 1) & 3) << 4);
    *(uint4*)((char*)As + srow * 64 + sw0) = a0;
    *(uint4*)((char*)As + (srow + 64) * 64 + sw1) = a1;
    *(uint4*)((char*)Bs + srow * 64 + sw0) = b0;
    *(uint4*)((char*)Bs + (srow + 64) * 64 + sw1) = b1;
    __syncthreads();
    short8 af[4], bfr[4];
#pragma unroll
    for (int m = 0; m < 4; ++m) {
      int row = wr * 64 + m * 16 + c;
      af[m] = ldfrag((const char*)As + row * 64 + ((g * 16) ^ (((row >> 1) & 3) << 4)));
    }
#pragma unroll
    for (int n = 0; n < 4; ++n) {
      int row = wc * 64 + n * 16 + c;
      bfr[n] = ldfrag((const char*)Bs + row * 64 + ((g * 16) ^ (((row >> 1) & 3) << 4)));
    }
#pragma unroll
    for (int m = 0; m < 4; ++m)
#pragma unroll
      for (int n = 0; n < 4; ++n) acc[m][n] = MFMA16(af[m], bfr[n], acc[m][n]);
  }

  const int row0 = bm * 128 + wr * 64 + 4 * g;
  const int col0 = bn * 128 + wc * 64 + c;
  if (sel < 2) {
    u16* out = sel ? Ok : Oq;
#pragma unroll
    for (int m = 0; m < 4; ++m)
#pragma unroll
      for (int n = 0; n < 4; ++n)
#pragma unroll
        for (int rr = 0; rr < 4; ++rr)
          out[(size_t)(row0 + m * 16 + rr) * N + col0 + n * 16] = f2b(acc[m][n][rr]);
  } else {
#pragma unroll
    for (int m = 0; m < 4; ++m)
#pragma unroll
      for (int n = 0; n < 4; ++n) {
        ushort4 o = { f2b(acc[m][n][0]), f2b(acc[m][n][1]), f2b(acc[m][n][2]), f2b(acc[m][n][3]) };
        *(ushort4*)(Ov + (size_t)(col0 + n * 16) * M + row0 + m * 16) = o;
      }
  }
}

// ---------------- reduce 4 split-K partials + bias + residual -> f32 ----------------
__global__ __launch_bounds__(256) void k_red4(const float* __restrict__ p,
                                              const float* __restrict__ bias,
                                              const float* __restrict__ resid,
                                              float* __restrict__ out) {
  int i = blockIdx.x * 256 + threadIdx.x;
  const float4* p4 = (const float4*)p;
  float4 a = p4[i], b = p4[i + 262144], c = p4[i + 524288], d = p4[i + 786432];
  float4 r = ((const float4*)resid)[i];
  float4 bb = ((const float4*)bias)[i & 63];
  float4 o;
  o.x = a.x + b.x + c.x + d.x + r.x + bb.x;
  o.y = a.y + b.y + c.y + d.y + r.y + bb.y;
  o.z = a.z + b.z + c.z + d.z + r.z + bb.z;
  o.w = a.w + b.w + c.w + d.w + r.w + bb.w;
  ((float4*)out)[i] = o;
}

// ---------------- fused: reduce 4 split-K partials + bias + resid -> x2, then LN -> bf16 ----------------
__global__ __launch_bounds__(256) void k_red4ln(const float* __restrict__ p,
                                                const float* __restrict__ bias,
                                                const float* __restrict__ resid,
                                                const float* __restrict__ g,
                                                const float* __restrict__ b,
                                                float* __restrict__ x2,
                                                u16* __restrict__ out) {
  int row = blockIdx.x * 4 + (threadIdx.x >> 6);
  int l = threadIdx.x & 63;
  int i = row * 64 + l;
  const float4* p4 = (const float4*)p;
  float4 a = p4[i], bq = p4[i + 262144], cq = p4[i + 524288], dq = p4[i + 786432];
  float4 r = ((const float4*)resid)[i];
  float4 bi = ((const float4*)bias)[l];
  float4 v;
  v.x = a.x + bq.x + cq.x + dq.x + r.x + bi.x;
  v.y = a.y + bq.y + cq.y + dq.y + r.y + bi.y;
  v.z = a.z + bq.z + cq.z + dq.z + r.z + bi.z;
  v.w = a.w + bq.w + cq.w + dq.w + r.w + bi.w;
  ((float4*)x2)[i] = v;
  float s = v.x + v.y + v.z + v.w;
#pragma unroll
  for (int m = 1; m < 64; m <<= 1) s += __shfl_xor(s, m);
  float mu = s * (1.0f / 256.0f);
  float dx = v.x - mu, dy = v.y - mu, dz = v.z - mu, dw = v.w - mu;
  float q = dx * dx + dy * dy + dz * dz + dw * dw;
#pragma unroll
  for (int m = 1; m < 64; m <<= 1) q += __shfl_xor(q, m);
  float rr = rsqrtf(q * (1.0f / 256.0f) + 1e-5f);
  float4 gv = *(const float4*)(g + l * 4);
  float4 bv = *(const float4*)(b + l * 4);
  ushort4 o = { f2b(dx * rr * gv.x + bv.x), f2b(dy * rr * gv.y + bv.y),
                f2b(dz * rr * gv.z + bv.z), f2b(dw * rr * gv.w + bv.w) };
  *(ushort4*)(out + (size_t)row * 256 + l * 4) = o;
}

// ---------------- Flash attention (kv-split-2): 8 heads, d_head=256, N=4096 ----------------
// R4 geometry (proven): 32x32x16 MFMA, swapped QK^T, 4 waves x 32 q, KVBLK=32, K+V double-buffered
// in 64KB LDS, 1 barrier/iter, 2 blocks/CU. Combined VGPR+AGPR budget = 256/wave: do not exceed.
// Additions vs R4: tree max/sum reductions, s_setprio around MFMA clusters.
__global__ __launch_bounds__(256, 2) void k_attn(const u16* __restrict__ Q,
                                                 const u16* __restrict__ Km,
                                                 const u16* __restrict__ VT,
                                                 u16* __restrict__ part,
                                                 float* __restrict__ ml) {
  __shared__ __attribute__((aligned(16))) char smem[65536];
  const int t = threadIdx.x;
  const int w = t >> 6, l = t & 63;
  const int q31 = l & 31, hi = l >> 5;
  const int head = blockIdx.x, qb = blockIdx.y, sp = blockIdx.z;
  const int kvbase = sp * 2048;
  const float C2 = 0.0625f * 1.44269504f;  // 1/sqrt(256) * log2(e)

  short8 qf[16];
  {
    const char* qp = (const char*)Q + (size_t)(qb * 128 + w * 32 + q31) * 4096 + head * 512 + hi * 16;
#pragma unroll
    for (int ks = 0; ks < 16; ++ks) qf[ks] = ldfrag(qp + ks * 32);
  }

  f32x16 o[8] = {};
  float m = -1e30f, lsum = 0.0f;

  const char* KbaseH = (const char*)Km + head * 512;
  const char* VbaseH = (const char*)VT + (size_t)head * 256 * 8192;

  auto stage = [&](int c) {
    const int buf = c & 1;
    const int kv0 = kvbase + c * 32;
    char* kd = smem + buf * 16384;
    char* vd = smem + 32768 + buf * 16384;
#pragma unroll
    for (int ii = 0; ii < 4; ++ii) {
      const int row = w * 8 + ii * 2 + hi;  // kv row; slot q31, source inverse-swizzled
      llds16(KbaseH + (size_t)(kv0 + row) * 4096 + ((q31 ^ row) << 4), kd + (w * 4 + ii) * 1024);
    }
#pragma unroll
    for (int ii = 0; ii < 4; ++ii) {
      const int row = w * 64 + ii * 16 + (l >> 2);  // d row; slot l&3
      llds16(VbaseH + (size_t)row * 8192 + (size_t)kv0 * 2 + (((l & 3) ^ ((row >> 3) & 3)) << 4),
             vd + (w * 4 + ii) * 1024);
    }
  };

  stage(0);
  for (int c = 0; c < 64; ++c) {
    asm volatile("s_waitcnt vmcnt(0)" ::: "memory");
    __builtin_amdgcn_s_barrier();
    __builtin_amdgcn_sched_barrier(0);
    if (c < 63) stage(c + 1);

    const char* kd = smem + (c & 1) * 16384;
    const char* vd = smem + 32768 + (c & 1) * 16384;

    // S^T = K . Q^T : C[kv][q], one 32-kv tile
    f32x16 s = {};
    const char* ka = kd + q31 * 512;
    const int sswz = q31 << 4;
    __builtin_amdgcn_s_setprio(1);
#pragma unroll
    for (int ks = 0; ks < 16; ++ks) {
      short8 a0 = ldfrag(ka + ((ks * 32 + hi * 16) ^ sswz));
      s = MFMA32(a0, qf[ks], s);
    }
    __builtin_amdgcn_s_setprio(0);

    // online softmax (kv lane-local), tree reductions, defer-max
    float m8[8];
#pragma unroll
    for (int i = 0; i < 8; ++i) m8[i] = fmaxf(s[i], s[i + 8]);
#pragma unroll
    for (int i = 0; i < 4; ++i) m8[i] = fmaxf(m8[i], m8[i + 4]);
    float pm = fmaxf(fmaxf(m8[0], m8[1]), fmaxf(m8[2], m8[3]));
    pm = fmaxf(pm, __shfl_xor(pm, 32));
    if (__any(pm > m + 64.0f)) {
      float mn = fmaxf(m, pm);
      float sc = EXP2((m - mn) * C2);
      m = mn;
      lsum *= sc;
#pragma unroll
      for (int i = 0; i < 16; ++i) {
        const int r = (i & 3) + 8 * (i >> 2) + 4 * hi;
        float sclr = __shfl(sc, r);
#pragma unroll
        for (int dt = 0; dt < 8; ++dt) o[dt][i] *= sclr;
      }
    }
    const float mc2 = m * C2;
    float p[16];
#pragma unroll
    for (int i = 0; i < 16; ++i) p[i] = EXP2(fmaf(s[i], C2, -mc2));
    float r8[8];
#pragma unroll
    for (int i = 0; i < 8; ++i) r8[i] = p[i] + p[i + 8];
#pragma unroll
    for (int i = 0; i < 4; ++i) r8[i] += r8[i + 4];
    float rs = (r8[0] + r8[1]) + (r8[2] + r8[3]);
    rs += __shfl_xor(rs, 32);
    lsum += rs;

    // in-register P -> A-fragments (q = lane&31; redistribute kv via permlane32_swap)
    u32 pk[8];
#pragma unroll
    for (int j = 0; j < 8; ++j)
      asm("v_cvt_pk_bf16_f32 %0, %1, %2" : "=v"(pk[j]) : "v"(p[2 * j]), "v"(p[2 * j + 1]));
    asm("v_permlane32_swap_b32 %0, %1" : "+v"(pk[0]), "+v"(pk[2]));
    asm("v_permlane32_swap_b32 %0, %1" : "+v"(pk[1]), "+v"(pk[3]));
    asm("v_permlane32_swap_b32 %0, %1" : "+v"(pk[4]), "+v"(pk[6]));
    asm("v_permlane32_swap_b32 %0, %1" : "+v"(pk[5]), "+v"(pk[7]));
    uint4 f0 = { pk[0], pk[1], pk[2], pk[3] };
    uint4 f1 = { pk[4], pk[5], pk[6], pk[7] };
    short8 pa0 = __builtin_bit_cast(short8, f0);
    short8 pa1 = __builtin_bit_cast(short8, f1);

    // O += P . V : B=V[kv][32d] from LDS (conflict-free swizzle), A=P in regs
    __builtin_amdgcn_s_setprio(1);
#pragma unroll
    for (int dt = 0; dt < 8; ++dt) {
      const int row = dt * 32 + q31;
      const char* vr = vd + row * 64;
      const int vs = ((row >> 3) & 3) << 4;
      short8 b0 = ldfrag(vr + ((hi * 16) ^ vs));
      short8 b1 = ldfrag(vr + ((32 + hi * 16) ^ vs));
      o[dt] = MFMA32(pa0, b0, o[dt]);
      o[dt] = MFMA32(pa1, b1, o[dt]);
    }
    __builtin_amdgcn_s_setprio(0);
  }

  // epilogue: unnormalized bf16 partial + (m, l)
  u16* pb = part + (size_t)sp * 4096 * 2048;
#pragma unroll
  for (int i = 0; i < 16; ++i) {
    const int r = (i & 3) + 8 * (i >> 2) + 4 * hi;
    const size_t qg = (size_t)(qb * 128 + w * 32 + r);
#pragma unroll
    for (int dt = 0; dt < 8; ++dt)
      pb[qg * 2048 + head * 256 + dt * 32 + q31] = f2b(o[dt][i]);
  }
  if (hi == 0) {
    const int qg = qb * 128 + w * 32 + q31;
    ml[((sp * 2 + 0) * 8 + head) * 4096 + qg] = m;
    ml[((sp * 2 + 1) * 8 + head) * 4096 + qg] = lsum;
  }
}

// ---------------- merge 2 kv-split partials ----------------
__global__ __launch_bounds__(256) void k_merge(const u16* __restrict__ part,
                                               const float* __restrict__ ml,
                                               u16* __restrict__ outp) {
  const int row = blockIdx.x;       // 4096
  const int t = threadIdx.x;        // 8 cols each
  const int c0 = t * 8;
  const int head = t >> 5;
  const float C2 = 0.0625f * 1.44269504f;
  float m0 = ml[(0 + head) * 4096 + row];
  float l0 = ml[(8 + head) * 4096 + row];
  float m1 = ml[(16 + head) * 4096 + row];
  float l1 = ml[(24 + head) * 4096 + row];
  float M = fmaxf(m0, m1);
  float w0 = EXP2((m0 - M) * C2), w1 = EXP2((m1 - M) * C2);
  float inv = 1.0f / (l0 * w0 + l1 * w1);
  w0 *= inv;
  w1 *= inv;
  const size_t base = (size_t)row * 2048 + c0;
  uint4 a = *(const uint4*)(part + base);
  uint4 b = *(const uint4*)(part + (size_t)4096 * 2048 + base);
  const u16* ah = (const u16*)&a;
  const u16* bh = (const u16*)&b;
  ushort4 o0, o1;
  u16* oh0 = (u16*)&o0;
  u16* oh1 = (u16*)&o1;
#pragma unroll
  for (int j = 0; j < 4; ++j) {
    oh0[j] = f2b(b2f(ah[j]) * w0 + b2f(bh[j]) * w1);
    oh1[j] = f2b(b2f(ah[j + 4]) * w0 + b2f(bh[j + 4]) * w1);
  }
  *(ushort4*)(outp + base) = o0;
  *(ushort4*)(outp + base + 4) = o1;
}

// ---------------- launch ----------------
extern "C" void kernel_launch(void* const* d_in, const int* in_sizes, int n_in,
                              void* d_out, int out_size, void* d_ws, size_t ws_size,
                              hipStream_t stream) {
  const float* x   = (const float*)d_in[0];
  const float* Wq  = (const float*)d_in[1];
  const float* Wk  = (const float*)d_in[2];
  const float* Wv  = (const float*)d_in[3];
  const float* Wo  = (const float*)d_in[4];
  const float* bo  = (const float*)d_in[5];
  const float* g1  = (const float*)d_in[6];
  const float* be1 = (const float*)d_in[7];
  const float* g2  = (const float*)d_in[8];
  const float* be2 = (const float*)d_in[9];
  const float* W1  = (const float*)d_in[10];
  const float* b1  = (const float*)d_in[11];
  const float* W2  = (const float*)d_in[12];
  const float* b2  = (const float*)d_in[13];

  char* ws = (char*)d_ws;
  size_t off = 0;
  auto alloc = [&](size_t n) {
    char* p = ws + off;
    off = (off + n + 255) & ~(size_t)255;
    return p;
  };
  u16* hb    = (u16*)alloc(4096 * 256 * 2);
  u16* Wqb   = (u16*)alloc(2048 * 256 * 2);
  u16* Wkb   = (u16*)alloc(2048 * 256 * 2);
  u16* Wvb   = (u16*)alloc(2048 * 256 * 2);
  u16* Wob   = (u16*)alloc(256 * 2048 * 2);
  u16* W1b   = (u16*)alloc(1024 * 256 * 2);
  u16* W2b   = (u16*)alloc(256 * 1024 * 2);
  u16* Qb    = (u16*)alloc((size_t)4096 * 2048 * 2);
  u16* Kb    = (u16*)alloc((size_t)4096 * 2048 * 2);
  u16* VTb   = (u16*)alloc((size_t)2048 * 4096 * 2);
  u16* attnb = (u16*)alloc((size_t)2 * 4096 * 2048 * 2);  // 2 kv-split partials; merged into slot 0
  float* mlb = (float*)alloc(32 * 4096 * 4);
  float* x2  = (float*)alloc(4096 * 256 * 4);
  u16* h2b   = (u16*)alloc(4096 * 256 * 2);
  u16* ffn1  = (u16*)alloc((size_t)4096 * 1024 * 2);
  float* pbuf = (float*)Qb;  // 16MB, dead after k_attn: 4x [4096][256] f32 split-K partials

  k_f2bm<<<dim3(512, 6), 256, 0, stream>>>(Wq, Wk, Wv, Wo, W1, W2, Wqb, Wkb, Wvb, Wob, W1b, W2b);

  k_ln<<<1024, 256, 0, stream>>>(x, g1, be1, hb);

  k_gemm_qkv<<<dim3(48, 32), 256, 0, stream>>>(hb, Wqb, Wkb, Wvb, Qb, Kb, VTb);

  k_attn<<<dim3(8, 32, 2), 256, 0, stream>>>(Qb, Kb, VTb, attnb, mlb);
  k_merge<<<4096, 256, 0, stream>>>(attnb, mlb, attnb);

  k_gemm<4><<<dim3(2, 32, 4), 256, 0, stream>>>(attnb, Wob, pbuf, nullptr, nullptr, 4096, 256, 2048);
  k_red4ln<<<1024, 256, 0, stream>>>(pbuf, bo, x, g2, be2, x2, h2b);
  k_gemm<3><<<dim3(8, 32), 256, 0, stream>>>(h2b, W1b, ffn1, b1, nullptr, 4096, 1024, 256);
  k_gemm<4><<<dim3(2, 32, 4), 256, 0, stream>>>(ffn1, W2b, pbuf, nullptr, nullptr, 4096, 256, 1024);
  k_red4<<<1024, 256, 0, stream>>>(pbuf, b2, x2, (float*)d_out);
}

// Round 7
// 265.894 us; speedup vs baseline: 1.2096x; 1.0186x over previous
//
#include <hip/hip_runtime.h>

typedef __attribute__((ext_vector_type(8))) short short8;
typedef __attribute__((ext_vector_type(4))) float f32x4;
typedef __attribute__((ext_vector_type(16))) float f32x16;
typedef unsigned short u16;
typedef unsigned int u32;

#define DEVFN static __device__ __forceinline__

DEVFN u16 f2b(float f) {
  u32 u = __builtin_bit_cast(u32, f);
  u32 r = u + 0x7fffu + ((u >> 16) & 1u);
  return (u16)(r >> 16);
}

DEVFN float b2f(u16 b) {
  u32 u = ((u32)b) << 16;
  return __builtin_bit_cast(float, u);
}

DEVFN short8 ldfrag(const void* p) {
  return __builtin_bit_cast(short8, *(const uint4*)p);
}

#define MFMA16(a, b, c) __builtin_amdgcn_mfma_f32_16x16x32_bf16((a), (b), (c), 0, 0, 0)
#define MFMA32(a, b, c) __builtin_amdgcn_mfma_f32_32x32x16_bf16((a), (b), (c), 0, 0, 0)
#define EXP2(x) __builtin_amdgcn_exp2f(x)

DEVFN void llds16(const void* g, void* l) {
  __builtin_amdgcn_global_load_lds((const __attribute__((address_space(1))) void*)g,
                                   (__attribute__((address_space(3))) void*)l, 16, 0, 0);
}

DEVFN float gelu_exact(float v) {
  return 0.5f * v * (1.0f + erff(v * 0.70710678118654752f));
}

// ---------------- fused: weight f32->bf16 (y<6) + LayerNorm1 (y==6) ----------------
__global__ __launch_bounds__(256) void k_prep(const float* s0, const float* s1, const float* s2,
                                              const float* s3, const float* s4, const float* s5,
                                              u16* d0, u16* d1, u16* d2, u16* d3, u16* d4, u16* d5,
                                              const float* x, const float* g1, const float* be1,
                                              u16* hb) {
  const int y = blockIdx.y;
  if (y < 6) {
    int i = blockIdx.x * 256 + threadIdx.x;
    const float* s;
    u16* d;
    int n4;
    switch (y) {
      case 0: s = s0; d = d0; n4 = 131072; break;
      case 1: s = s1; d = d1; n4 = 131072; break;
      case 2: s = s2; d = d2; n4 = 131072; break;
      case 3: s = s3; d = d3; n4 = 131072; break;
      case 4: s = s4; d = d4; n4 = 65536; break;
      default: s = s5; d = d5; n4 = 65536; break;
    }
    if (i >= n4) return;
    float4 v = ((const float4*)s)[i];
    ushort4 o = { f2b(v.x), f2b(v.y), f2b(v.z), f2b(v.w) };
    ((ushort4*)d)[i] = o;
    return;
  }
  // LayerNorm1
  int row = blockIdx.x * 4 + (threadIdx.x >> 6);
  int l = threadIdx.x & 63;
  const float4 v = *(const float4*)(x + (size_t)row * 256 + l * 4);
  float s = v.x + v.y + v.z + v.w;
#pragma unroll
  for (int m = 1; m < 64; m <<= 1) s += __shfl_xor(s, m);
  float mu = s * (1.0f / 256.0f);
  float dx = v.x - mu, dy = v.y - mu, dz = v.z - mu, dw = v.w - mu;
  float q = dx * dx + dy * dy + dz * dz + dw * dw;
#pragma unroll
  for (int m = 1; m < 64; m <<= 1) q += __shfl_xor(q, m);
  float r = rsqrtf(q * (1.0f / 256.0f) + 1e-5f);
  float4 gv = *(const float4*)(g1 + l * 4);
  float4 bv = *(const float4*)(be1 + l * 4);
  ushort4 o = { f2b(dx * r * gv.x + bv.x), f2b(dy * r * gv.y + bv.y),
                f2b(dz * r * gv.z + bv.z), f2b(dw * r * gv.w + bv.w) };
  *(ushort4*)(hb + (size_t)row * 256 + l * 4) = o;
}

// ---------------- GEMM: C[M,N] = A[M,K] * B[N,K]^T, bf16 inputs ----------------
// EPI 3: bf16 + bias + GELU    EPI 4: f32 partial (split-K over gridDim.z)
template <int EPI>
__global__ __launch_bounds__(256, 2) void k_gemm(const u16* __restrict__ A,
                                                 const u16* __restrict__ B,
                                                 void* __restrict__ out,
                                                 const float* __restrict__ bias,
                                                 int M, int N, int K) {
  __shared__ __attribute__((aligned(16))) u16 As[128 * 32];
  __shared__ __attribute__((aligned(16))) u16 Bs[128 * 32];
  const int t = threadIdx.x;
  const int w = t >> 6, l = t & 63, g = l >> 4, c = l & 15;
  const int wr = w >> 1, wc = w & 1;
  const int bm = blockIdx.y, bn = blockIdx.x;

  f32x4 acc[4][4] = {};
  int nk = K >> 5, kk0 = 0;
  if (EPI == 4) { nk = nk / gridDim.z; kk0 = blockIdx.z * nk; }

  const int srow = t >> 2;
  const int sj = t & 3;
  const char* Abase = (const char*)A;
  const char* Bbase = (const char*)B;

  for (int kk = kk0; kk < kk0 + nk; ++kk) {
    const size_t kb = (size_t)kk * 64;
    uint4 a0 = *(const uint4*)(Abase + ((size_t)(bm * 128 + srow) * K) * 2 + kb + sj * 16);
    uint4 a1 = *(const uint4*)(Abase + ((size_t)(bm * 128 + srow + 64) * K) * 2 + kb + sj * 16);
    uint4 b0 = *(const uint4*)(Bbase + ((size_t)(bn * 128 + srow) * K) * 2 + kb + sj * 16);
    uint4 b1 = *(const uint4*)(Bbase + ((size_t)(bn * 128 + srow + 64) * K) * 2 + kb + sj * 16);
    __syncthreads();
    const int sw0 = (sj * 16) ^ (((srow >> 1) & 3) << 4);
    const int sw1 = (sj * 16) ^ ((((srow + 64) >> 1) & 3) << 4);
    *(uint4*)((char*)As + srow * 64 + sw0) = a0;
    *(uint4*)((char*)As + (srow + 64) * 64 + sw1) = a1;
    *(uint4*)((char*)Bs + srow * 64 + sw0) = b0;
    *(uint4*)((char*)Bs + (srow + 64) * 64 + sw1) = b1;
    __syncthreads();
    short8 af[4], bfr[4];
#pragma unroll
    for (int m = 0; m < 4; ++m) {
      int row = wr * 64 + m * 16 + c;
      af[m] = ldfrag((const char*)As + row * 64 + ((g * 16) ^ (((row >> 1) & 3) << 4)));
    }
#pragma unroll
    for (int n = 0; n < 4; ++n) {
      int row = wc * 64 + n * 16 + c;
      bfr[n] = ldfrag((const char*)Bs + row * 64 + ((g * 16) ^ (((row >> 1) & 3) << 4)));
    }
#pragma unroll
    for (int m = 0; m < 4; ++m)
#pragma unroll
      for (int n = 0; n < 4; ++n) acc[m][n] = MFMA16(af[m], bfr[n], acc[m][n]);
  }

  const int row0 = bm * 128 + wr * 64 + 4 * g;
  const int col0 = bn * 128 + wc * 64 + c;
#pragma unroll
  for (int m = 0; m < 4; ++m) {
#pragma unroll
    for (int n = 0; n < 4; ++n) {
      const int row = row0 + m * 16;
      const int col = col0 + n * 16;
      if (EPI == 3) {
        float bc = bias[col];
#pragma unroll
        for (int rr = 0; rr < 4; ++rr)
          ((u16*)out)[(size_t)(row + rr) * N + col] = f2b(gelu_exact(acc[m][n][rr] + bc));
      } else {
        float* po = (float*)out + (size_t)blockIdx.z * M * N;
#pragma unroll
        for (int rr = 0; rr < 4; ++rr)
          po[(size_t)(row + rr) * N + col] = acc[m][n][rr];
      }
    }
  }
}

// ---------------- Wo GEMM with fused kv-split merge in A-staging ----------------
// A = merge(part0, part1) per (row, head); B = Wob [256][2048]; out f32 partials [z][4096][256].
// grid (2, 32, 4): z splits K=2048 into 16 kk-iters (2 heads per z).
__global__ __launch_bounds__(256, 2) void k_gemm_wo(const u16* __restrict__ part,
                                                    const float* __restrict__ ml,
                                                    const u16* __restrict__ B,
                                                    float* __restrict__ out) {
  constexpr int M = 4096, N = 256, K = 2048;
  __shared__ __attribute__((aligned(16))) u16 As[128 * 32];
  __shared__ __attribute__((aligned(16))) u16 Bs[128 * 32];
  const int t = threadIdx.x;
  const int w = t >> 6, l = t & 63, g = l >> 4, c = l & 15;
  const int wr = w >> 1, wc = w & 1;
  const int bm = blockIdx.y, bn = blockIdx.x;
  const int nk = 16, kk0 = blockIdx.z * 16;
  const int h0 = kk0 >> 3;  // heads h0, h0+1 within this z-slice
  const float C2 = 0.0625f * 1.44269504f;

  const int srow = t >> 2;
  const int sj = t & 3;
  const int r0 = bm * 128 + srow, r1 = r0 + 64;

  // per-thread merge weights: rows {r0,r1} x heads {h0,h0+1} x parts {0,1}
  float wgt[8];
#pragma unroll
  for (int rr = 0; rr < 2; ++rr) {
    const int row = rr ? r1 : r0;
#pragma unroll
    for (int hh = 0; hh < 2; ++hh) {
      const int h = h0 + hh;
      float m0 = ml[(0 + h) * 4096 + row];
      float l0 = ml[(8 + h) * 4096 + row];
      float m1 = ml[(16 + h) * 4096 + row];
      float l1 = ml[(24 + h) * 4096 + row];
      float Mx = fmaxf(m0, m1);
      float w0 = EXP2((m0 - Mx) * C2), w1 = EXP2((m1 - Mx) * C2);
      float inv = 1.0f / (l0 * w0 + l1 * w1);
      wgt[rr * 4 + hh * 2 + 0] = w0 * inv;
      wgt[rr * 4 + hh * 2 + 1] = w1 * inv;
    }
  }

  f32x4 acc[4][4] = {};
  const char* Pbase = (const char*)part;
  const char* Bbase = (const char*)B;
  const size_t PSTRIDE = (size_t)4096 * 2048 * 2;

  for (int kk = kk0; kk < kk0 + nk; ++kk) {
    const int hh = (kk >> 3) & 1;
    const size_t kb = (size_t)kk * 64;
    const size_t a0off = ((size_t)r0 * K) * 2 + kb + sj * 16;
    const size_t a1off = ((size_t)r1 * K) * 2 + kb + sj * 16;
    uint4 p00 = *(const uint4*)(Pbase + a0off);
    uint4 p01 = *(const uint4*)(Pbase + PSTRIDE + a0off);
    uint4 p10 = *(const uint4*)(Pbase + a1off);
    uint4 p11 = *(const uint4*)(Pbase + PSTRIDE + a1off);
    uint4 b0 = *(const uint4*)(Bbase + ((size_t)(bn * 128 + srow) * K) * 2 + kb + sj * 16);
    uint4 b1 = *(const uint4*)(Bbase + ((size_t)(bn * 128 + srow + 64) * K) * 2 + kb + sj * 16);

    float w00 = hh ? wgt[2] : wgt[0], w01 = hh ? wgt[3] : wgt[1];
    float w10 = hh ? wgt[6] : wgt[4], w11 = hh ? wgt[7] : wgt[5];
    uint4 a0, a1;
    {
      const u16* x0 = (const u16*)&p00;
      const u16* x1 = (const u16*)&p01;
      u16* o = (u16*)&a0;
#pragma unroll
      for (int j = 0; j < 8; ++j) o[j] = f2b(b2f(x0[j]) * w00 + b2f(x1[j]) * w01);
      const u16* y0 = (const u16*)&p10;
      const u16* y1 = (const u16*)&p11;
      u16* o1 = (u16*)&a1;
#pragma unroll
      for (int j = 0; j < 8; ++j) o1[j] = f2b(b2f(y0[j]) * w10 + b2f(y1[j]) * w11);
    }

    __syncthreads();
    const int sw0 = (sj * 16) ^ (((srow >> 1) & 3) << 4);
    const int sw1 = (sj * 16) ^ ((((srow + 64) >> 1) & 3) << 4);
    *(uint4*)((char*)As + srow * 64 + sw0) = a0;
    *(uint4*)((char*)As + (srow + 64) * 64 + sw1) = a1;
    *(uint4*)((char*)Bs + srow * 64 + sw0) = b0;
    *(uint4*)((char*)Bs + (srow + 64) * 64 + sw1) = b1;
    __syncthreads();
    short8 af[4], bfr[4];
#pragma unroll
    for (int m = 0; m < 4; ++m) {
      int row = wr * 64 + m * 16 + c;
      af[m] = ldfrag((const char*)As + row * 64 + ((g * 16) ^ (((row >> 1) & 3) << 4)));
    }
#pragma unroll
    for (int n = 0; n < 4; ++n) {
      int row = wc * 64 + n * 16 + c;
      bfr[n] = ldfrag((const char*)Bs + row * 64 + ((g * 16) ^ (((row >> 1) & 3) << 4)));
    }
#pragma unroll
    for (int m = 0; m < 4; ++m)
#pragma unroll
      for (int n = 0; n < 4; ++n) acc[m][n] = MFMA16(af[m], bfr[n], acc[m][n]);
  }

  const int row0 = bm * 128 + wr * 64 + 4 * g;
  const int col0 = bn * 128 + wc * 64 + c;
  float* po = out + (size_t)blockIdx.z * M * N;
#pragma unroll
  for (int m = 0; m < 4; ++m)
#pragma unroll
    for (int n = 0; n < 4; ++n)
#pragma unroll
      for (int rr = 0; rr < 4; ++rr)
        po[(size_t)(row0 + m * 16 + rr) * N + col0 + n * 16] = acc[m][n][rr];
}

// ---------------- merged QKV GEMM: 3 outputs, shared A; sel 2 stores transposed ----------------
__global__ __launch_bounds__(256, 2) void k_gemm_qkv(const u16* __restrict__ A,
                                                     const u16* __restrict__ Bq,
                                                     const u16* __restrict__ Bk,
                                                     const u16* __restrict__ Bv,
                                                     u16* __restrict__ Oq,
                                                     u16* __restrict__ Ok,
                                                     u16* __restrict__ Ov) {
  constexpr int M = 4096, N = 2048, K = 256;
  __shared__ __attribute__((aligned(16))) u16 As[128 * 32];
  __shared__ __attribute__((aligned(16))) u16 Bs[128 * 32];
  const int t = threadIdx.x;
  const int w = t >> 6, l = t & 63, g = l >> 4, c = l & 15;
  const int wr = w >> 1, wc = w & 1;
  const int sel = blockIdx.x >> 4;
  const int bn = blockIdx.x & 15;
  const int bm = blockIdx.y;
  const u16* B = sel == 0 ? Bq : (sel == 1 ? Bk : Bv);

  f32x4 acc[4][4] = {};
  const int srow = t >> 2;
  const int sj = t & 3;
  const char* Abase = (const char*)A;
  const char* Bbase = (const char*)B;

  for (int kk = 0; kk < 8; ++kk) {
    const size_t kb = (size_t)kk * 64;
    uint4 a0 = *(const uint4*)(Abase + ((size_t)(bm * 128 + srow) * K) * 2 + kb + sj * 16);
    uint4 a1 = *(const uint4*)(Abase + ((size_t)(bm * 128 + srow + 64) * K) * 2 + kb + sj * 16);
    uint4 b0 = *(const uint4*)(Bbase + ((size_t)(bn * 128 + srow) * K) * 2 + kb + sj * 16);
    uint4 b1 = *(const uint4*)(Bbase + ((size_t)(bn * 128 + srow + 64) * K) * 2 + kb + sj * 16);
    __syncthreads();
    const int sw0 = (sj * 16) ^ (((srow >> 1) & 3) << 4);
    const int sw1 = (sj * 16) ^ ((((srow + 64) >> 1) & 3) << 4);
    *(uint4*)((char*)As + srow * 64 + sw0) = a0;
    *(uint4*)((char*)As + (srow + 64) * 64 + sw1) = a1;
    *(uint4*)((char*)Bs + srow * 64 + sw0) = b0;
    *(uint4*)((char*)Bs + (srow + 64) * 64 + sw1) = b1;
    __syncthreads();
    short8 af[4], bfr[4];
#pragma unroll
    for (int m = 0; m < 4; ++m) {
      int row = wr * 64 + m * 16 + c;
      af[m] = ldfrag((const char*)As + row * 64 + ((g * 16) ^ (((row >> 1) & 3) << 4)));
    }
#pragma unroll
    for (int n = 0; n < 4; ++n) {
      int row = wc * 64 + n * 16 + c;
      bfr[n] = ldfrag((const char*)Bs + row * 64 + ((g * 16) ^ (((row >> 1) & 3) << 4)));
    }
#pragma unroll
    for (int m = 0; m < 4; ++m)
#pragma unroll
      for (int n = 0; n < 4; ++n) acc[m][n] = MFMA16(af[m], bfr[n], acc[m][n]);
  }

  const int row0 = bm * 128 + wr * 64 + 4 * g;
  const int col0 = bn * 128 + wc * 64 + c;
  if (sel < 2) {
    u16* out = sel ? Ok : Oq;
#pragma unroll
    for (int m = 0; m < 4; ++m)
#pragma unroll
      for (int n = 0; n < 4; ++n)
#pragma unroll
        for (int rr = 0; rr < 4; ++rr)
          out[(size_t)(row0 + m * 16 + rr) * N + col0 + n * 16] = f2b(acc[m][n][rr]);
  } else {
#pragma unroll
    for (int m = 0; m < 4; ++m)
#pragma unroll
      for (int n = 0; n < 4; ++n) {
        ushort4 o = { f2b(acc[m][n][0]), f2b(acc[m][n][1]), f2b(acc[m][n][2]), f2b(acc[m][n][3]) };
        *(ushort4*)(Ov + (size_t)(col0 + n * 16) * M + row0 + m * 16) = o;
      }
  }
}

// ---------------- reduce 4 split-K partials + bias + residual -> f32 ----------------
__global__ __launch_bounds__(256) void k_red4(const float* __restrict__ p,
                                              const float* __restrict__ bias,
                                              const float* __restrict__ resid,
                                              float* __restrict__ out) {
  int i = blockIdx.x * 256 + threadIdx.x;
  const float4* p4 = (const float4*)p;
  float4 a = p4[i], b = p4[i + 262144], c = p4[i + 524288], d = p4[i + 786432];
  float4 r = ((const float4*)resid)[i];
  float4 bb = ((const float4*)bias)[i & 63];
  float4 o;
  o.x = a.x + b.x + c.x + d.x + r.x + bb.x;
  o.y = a.y + b.y + c.y + d.y + r.y + bb.y;
  o.z = a.z + b.z + c.z + d.z + r.z + bb.z;
  o.w = a.w + b.w + c.w + d.w + r.w + bb.w;
  ((float4*)out)[i] = o;
}

// ---------------- fused: reduce 4 split-K partials + bias + resid -> x2, then LN -> bf16 ----------------
__global__ __launch_bounds__(256) void k_red4ln(const float* __restrict__ p,
                                                const float* __restrict__ bias,
                                                const float* __restrict__ resid,
                                                const float* __restrict__ g,
                                                const float* __restrict__ b,
                                                float* __restrict__ x2,
                                                u16* __restrict__ out) {
  int row = blockIdx.x * 4 + (threadIdx.x >> 6);
  int l = threadIdx.x & 63;
  int i = row * 64 + l;
  const float4* p4 = (const float4*)p;
  float4 a = p4[i], bq = p4[i + 262144], cq = p4[i + 524288], dq = p4[i + 786432];
  float4 r = ((const float4*)resid)[i];
  float4 bi = ((const float4*)bias)[l];
  float4 v;
  v.x = a.x + bq.x + cq.x + dq.x + r.x + bi.x;
  v.y = a.y + bq.y + cq.y + dq.y + r.y + bi.y;
  v.z = a.z + bq.z + cq.z + dq.z + r.z + bi.z;
  v.w = a.w + bq.w + cq.w + dq.w + r.w + bi.w;
  ((float4*)x2)[i] = v;
  float s = v.x + v.y + v.z + v.w;
#pragma unroll
  for (int m = 1; m < 64; m <<= 1) s += __shfl_xor(s, m);
  float mu = s * (1.0f / 256.0f);
  float dx = v.x - mu, dy = v.y - mu, dz = v.z - mu, dw = v.w - mu;
  float q = dx * dx + dy * dy + dz * dz + dw * dw;
#pragma unroll
  for (int m = 1; m < 64; m <<= 1) q += __shfl_xor(q, m);
  float rr = rsqrtf(q * (1.0f / 256.0f) + 1e-5f);
  float4 gv = *(const float4*)(g + l * 4);
  float4 bv = *(const float4*)(b + l * 4);
  ushort4 o = { f2b(dx * rr * gv.x + bv.x), f2b(dy * rr * gv.y + bv.y),
                f2b(dz * rr * gv.z + bv.z), f2b(dw * rr * gv.w + bv.w) };
  *(ushort4*)(out + (size_t)row * 256 + l * 4) = o;
}

// ---------------- Flash attention (kv-split-2): 8 heads, d_head=256, N=4096 ----------------
// Proven geometry: 32x32x16 MFMA, swapped QK^T, 4 waves x 32 q, KVBLK=32, K+V double-buffered
// in 64KB LDS, 1 barrier/iter, 2 blocks/CU. Combined VGPR+AGPR = 256/wave: do not exceed.
__global__ __launch_bounds__(256, 2) void k_attn(const u16* __restrict__ Q,
                                                 const u16* __restrict__ Km,
                                                 const u16* __restrict__ VT,
                                                 u16* __restrict__ part,
                                                 float* __restrict__ ml) {
  __shared__ __attribute__((aligned(16))) char smem[65536];
  const int t = threadIdx.x;
  const int w = t >> 6, l = t & 63;
  const int q31 = l & 31, hi = l >> 5;
  const int head = blockIdx.x, qb = blockIdx.y, sp = blockIdx.z;
  const int kvbase = sp * 2048;
  const float C2 = 0.0625f * 1.44269504f;  // 1/sqrt(256) * log2(e)

  short8 qf[16];
  {
    const char* qp = (const char*)Q + (size_t)(qb * 128 + w * 32 + q31) * 4096 + head * 512 + hi * 16;
#pragma unroll
    for (int ks = 0; ks < 16; ++ks) qf[ks] = ldfrag(qp + ks * 32);
  }

  f32x16 o[8] = {};
  float m = -1e30f, lsum = 0.0f;

  const char* KbaseH = (const char*)Km + head * 512;
  const char* VbaseH = (const char*)VT + (size_t)head * 256 * 8192;

  auto stage = [&](int c) {
    const int buf = c & 1;
    const int kv0 = kvbase + c * 32;
    char* kd = smem + buf * 16384;
    char* vd = smem + 32768 + buf * 16384;
#pragma unroll
    for (int ii = 0; ii < 4; ++ii) {
      const int row = w * 8 + ii * 2 + hi;
      llds16(KbaseH + (size_t)(kv0 + row) * 4096 + ((q31 ^ row) << 4), kd + (w * 4 + ii) * 1024);
    }
#pragma unroll
    for (int ii = 0; ii < 4; ++ii) {
      const int row = w * 64 + ii * 16 + (l >> 2);
      llds16(VbaseH + (size_t)row * 8192 + (size_t)kv0 * 2 + (((l & 3) ^ ((row >> 3) & 3)) << 4),
             vd + (w * 4 + ii) * 1024);
    }
  };

  stage(0);
  for (int c = 0; c < 64; ++c) {
    asm volatile("s_waitcnt vmcnt(0)" ::: "memory");
    __builtin_amdgcn_s_barrier();
    __builtin_amdgcn_sched_barrier(0);
    if (c < 63) stage(c + 1);

    const char* kd = smem + (c & 1) * 16384;
    const char* vd = smem + 32768 + (c & 1) * 16384;

    f32x16 s = {};
    const char* ka = kd + q31 * 512;
    const int sswz = q31 << 4;
    __builtin_amdgcn_s_setprio(1);
#pragma unroll
    for (int ks = 0; ks < 16; ++ks) {
      short8 a0 = ldfrag(ka + ((ks * 32 + hi * 16) ^ sswz));
      s = MFMA32(a0, qf[ks], s);
    }
    __builtin_amdgcn_s_setprio(0);

    float m8[8];
#pragma unroll
    for (int i = 0; i < 8; ++i) m8[i] = fmaxf(s[i], s[i + 8]);
#pragma unroll
    for (int i = 0; i < 4; ++i) m8[i] = fmaxf(m8[i], m8[i + 4]);
    float pm = fmaxf(fmaxf(m8[0], m8[1]), fmaxf(m8[2], m8[3]));
    pm = fmaxf(pm, __shfl_xor(pm, 32));
    if (__any(pm > m + 64.0f)) {
      float mn = fmaxf(m, pm);
      float sc = EXP2((m - mn) * C2);
      m = mn;
      lsum *= sc;
#pragma unroll
      for (int i = 0; i < 16; ++i) {
        const int r = (i & 3) + 8 * (i >> 2) + 4 * hi;
        float sclr = __shfl(sc, r);
#pragma unroll
        for (int dt = 0; dt < 8; ++dt) o[dt][i] *= sclr;
      }
    }
    const float mc2 = m * C2;
    float p[16];
#pragma unroll
    for (int i = 0; i < 16; ++i) p[i] = EXP2(fmaf(s[i], C2, -mc2));
    float r8[8];
#pragma unroll
    for (int i = 0; i < 8; ++i) r8[i] = p[i] + p[i + 8];
#pragma unroll
    for (int i = 0; i < 4; ++i) r8[i] += r8[i + 4];
    float rs = (r8[0] + r8[1]) + (r8[2] + r8[3]);
    rs += __shfl_xor(rs, 32);
    lsum += rs;

    u32 pk[8];
#pragma unroll
    for (int j = 0; j < 8; ++j)
      asm("v_cvt_pk_bf16_f32 %0, %1, %2" : "=v"(pk[j]) : "v"(p[2 * j]), "v"(p[2 * j + 1]));
    asm("v_permlane32_swap_b32 %0, %1" : "+v"(pk[0]), "+v"(pk[2]));
    asm("v_permlane32_swap_b32 %0, %1" : "+v"(pk[1]), "+v"(pk[3]));
    asm("v_permlane32_swap_b32 %0, %1" : "+v"(pk[4]), "+v"(pk[6]));
    asm("v_permlane32_swap_b32 %0, %1" : "+v"(pk[5]), "+v"(pk[7]));
    uint4 f0 = { pk[0], pk[1], pk[2], pk[3] };
    uint4 f1 = { pk[4], pk[5], pk[6], pk[7] };
    short8 pa0 = __builtin_bit_cast(short8, f0);
    short8 pa1 = __builtin_bit_cast(short8, f1);

    __builtin_amdgcn_s_setprio(1);
#pragma unroll
    for (int dt = 0; dt < 8; ++dt) {
      const int row = dt * 32 + q31;
      const char* vr = vd + row * 64;
      const int vs = ((row >> 3) & 3) << 4;
      short8 b0 = ldfrag(vr + ((hi * 16) ^ vs));
      short8 b1 = ldfrag(vr + ((32 + hi * 16) ^ vs));
      o[dt] = MFMA32(pa0, b0, o[dt]);
      o[dt] = MFMA32(pa1, b1, o[dt]);
    }
    __builtin_amdgcn_s_setprio(0);
  }

  u16* pb = part + (size_t)sp * 4096 * 2048;
#pragma unroll
  for (int i = 0; i < 16; ++i) {
    const int r = (i & 3) + 8 * (i >> 2) + 4 * hi;
    const size_t qg = (size_t)(qb * 128 + w * 32 + r);
#pragma unroll
    for (int dt = 0; dt < 8; ++dt)
      pb[qg * 2048 + head * 256 + dt * 32 + q31] = f2b(o[dt][i]);
  }
  if (hi == 0) {
    const int qg = qb * 128 + w * 32 + q31;
    ml[((sp * 2 + 0) * 8 + head) * 4096 + qg] = m;
    ml[((sp * 2 + 1) * 8 + head) * 4096 + qg] = lsum;
  }
}

// ---------------- launch ----------------
extern "C" void kernel_launch(void* const* d_in, const int* in_sizes, int n_in,
                              void* d_out, int out_size, void* d_ws, size_t ws_size,
                              hipStream_t stream) {
  const float* x   = (const float*)d_in[0];
  const float* Wq  = (const float*)d_in[1];
  const float* Wk  = (const float*)d_in[2];
  const float* Wv  = (const float*)d_in[3];
  const float* Wo  = (const float*)d_in[4];
  const float* bo  = (const float*)d_in[5];
  const float* g1  = (const float*)d_in[6];
  const float* be1 = (const float*)d_in[7];
  const float* g2  = (const float*)d_in[8];
  const float* be2 = (const float*)d_in[9];
  const float* W1  = (const float*)d_in[10];
  const float* b1  = (const float*)d_in[11];
  const float* W2  = (const float*)d_in[12];
  const float* b2  = (const float*)d_in[13];

  char* ws = (char*)d_ws;
  size_t off = 0;
  auto alloc = [&](size_t n) {
    char* p = ws + off;
    off = (off + n + 255) & ~(size_t)255;
    return p;
  };
  u16* hb    = (u16*)alloc(4096 * 256 * 2);
  u16* Wqb   = (u16*)alloc(2048 * 256 * 2);
  u16* Wkb   = (u16*)alloc(2048 * 256 * 2);
  u16* Wvb   = (u16*)alloc(2048 * 256 * 2);
  u16* Wob   = (u16*)alloc(256 * 2048 * 2);
  u16* W1b   = (u16*)alloc(1024 * 256 * 2);
  u16* W2b   = (u16*)alloc(256 * 1024 * 2);
  u16* Qb    = (u16*)alloc((size_t)4096 * 2048 * 2);
  u16* Kb    = (u16*)alloc((size_t)4096 * 2048 * 2);
  u16* VTb   = (u16*)alloc((size_t)2048 * 4096 * 2);
  u16* attnb = (u16*)alloc((size_t)2 * 4096 * 2048 * 2);  // 2 kv-split partials (merged in Wo GEMM)
  float* mlb = (float*)alloc(32 * 4096 * 4);
  float* x2  = (float*)alloc(4096 * 256 * 4);
  u16* h2b   = (u16*)alloc(4096 * 256 * 2);
  u16* ffn1  = (u16*)alloc((size_t)4096 * 1024 * 2);
  float* pbuf = (float*)Qb;  // 16MB, dead after k_attn: 4x [4096][256] f32 split-K partials

  k_prep<<<dim3(1024, 7), 256, 0, stream>>>(Wq, Wk, Wv, Wo, W1, W2,
                                            Wqb, Wkb, Wvb, Wob, W1b, W2b,
                                            x, g1, be1, hb);

  k_gemm_qkv<<<dim3(48, 32), 256, 0, stream>>>(hb, Wqb, Wkb, Wvb, Qb, Kb, VTb);

  k_attn<<<dim3(8, 32, 2), 256, 0, stream>>>(Qb, Kb, VTb, attnb, mlb);

  k_gemm_wo<<<dim3(2, 32, 4), 256, 0, stream>>>(attnb, mlb, Wob, pbuf);
  k_red4ln<<<1024, 256, 0, stream>>>(pbuf, bo, x, g2, be2, x2, h2b);
  k_gemm<3><<<dim3(8, 32), 256, 0, stream>>>(h2b, W1b, ffn1, b1, 4096, 1024, 256);
  k_gemm<4><<<dim3(2, 32, 4), 256, 0, stream>>>(ffn1, W2b, pbuf, nullptr, 4096, 256, 1024);
  k_red4<<<1024, 256, 0, stream>>>(pbuf, b2, x2, (float*)d_out);
}

// Round 8
// 214.517 us; speedup vs baseline: 1.4993x; 1.2395x over previous
//
#include <hip/hip_runtime.h>

typedef __attribute__((ext_vector_type(8))) short short8;
typedef __attribute__((ext_vector_type(4))) float f32x4;
typedef __attribute__((ext_vector_type(16))) float f32x16;
typedef __attribute__((ext_vector_type(2))) unsigned int u32x2;
typedef unsigned short u16;
typedef unsigned int u32;
typedef unsigned char u8;

#define DEVFN static __device__ __forceinline__

DEVFN u16 f2b(float f) {
  u32 u = __builtin_bit_cast(u32, f);
  u32 r = u + 0x7fffu + ((u >> 16) & 1u);
  return (u16)(r >> 16);
}

DEVFN float b2f(u16 b) {
  u32 u = ((u32)b) << 16;
  return __builtin_bit_cast(float, u);
}

DEVFN short8 ldfrag(const void* p) {
  return __builtin_bit_cast(short8, *(const uint4*)p);
}

#define MFMA16(a, b, c) __builtin_amdgcn_mfma_f32_16x16x32_bf16((a), (b), (c), 0, 0, 0)
#define MFMA32(a, b, c) __builtin_amdgcn_mfma_f32_32x32x16_bf16((a), (b), (c), 0, 0, 0)
#define MFMA8(a, b, c) __builtin_amdgcn_mfma_f32_32x32x16_fp8_fp8((a), (b), (c), 0, 0, 0)
#define EXP2(x) __builtin_amdgcn_exp2f(x)

DEVFN void llds16(const void* g, void* l) {
  __builtin_amdgcn_global_load_lds((const __attribute__((address_space(1))) void*)g,
                                   (__attribute__((address_space(3))) void*)l, 16, 0, 0);
}

DEVFN float gelu_exact(float v) {
  return 0.5f * v * (1.0f + erff(v * 0.70710678118654752f));
}

// sigma: swap bits 3 and 4 of d (involution) — interleaves d so one 16B read feeds 2 fp8 MFMA frags
DEVFN int sigma(int d) {
  return (d & 0xE7) | ((d & 8) << 1) | ((d & 16) >> 1);
}

// ---------------- fused: weight f32->bf16 (y<6) + LayerNorm1 (y==6) ----------------
__global__ __launch_bounds__(256) void k_prep(const float* s0, const float* s1, const float* s2,
                                              const float* s3, const float* s4, const float* s5,
                                              u16* d0, u16* d1, u16* d2, u16* d3, u16* d4, u16* d5,
                                              const float* x, const float* g1, const float* be1,
                                              u16* hb) {
  const int y = blockIdx.y;
  if (y < 6) {
    int i = blockIdx.x * 256 + threadIdx.x;
    const float* s;
    u16* d;
    int n4;
    switch (y) {
      case 0: s = s0; d = d0; n4 = 131072; break;
      case 1: s = s1; d = d1; n4 = 131072; break;
      case 2: s = s2; d = d2; n4 = 131072; break;
      case 3: s = s3; d = d3; n4 = 131072; break;
      case 4: s = s4; d = d4; n4 = 65536; break;
      default: s = s5; d = d5; n4 = 65536; break;
    }
    if (i >= n4) return;
    float4 v = ((const float4*)s)[i];
    ushort4 o = { f2b(v.x), f2b(v.y), f2b(v.z), f2b(v.w) };
    ((ushort4*)d)[i] = o;
    return;
  }
  int row = blockIdx.x * 4 + (threadIdx.x >> 6);
  int l = threadIdx.x & 63;
  const float4 v = *(const float4*)(x + (size_t)row * 256 + l * 4);
  float s = v.x + v.y + v.z + v.w;
#pragma unroll
  for (int m = 1; m < 64; m <<= 1) s += __shfl_xor(s, m);
  float mu = s * (1.0f / 256.0f);
  float dx = v.x - mu, dy = v.y - mu, dz = v.z - mu, dw = v.w - mu;
  float q = dx * dx + dy * dy + dz * dz + dw * dw;
#pragma unroll
  for (int m = 1; m < 64; m <<= 1) q += __shfl_xor(q, m);
  float r = rsqrtf(q * (1.0f / 256.0f) + 1e-5f);
  float4 gv = *(const float4*)(g1 + l * 4);
  float4 bv = *(const float4*)(be1 + l * 4);
  ushort4 o = { f2b(dx * r * gv.x + bv.x), f2b(dy * r * gv.y + bv.y),
                f2b(dz * r * gv.z + bv.z), f2b(dw * r * gv.w + bv.w) };
  *(ushort4*)(hb + (size_t)row * 256 + l * 4) = o;
}

// ---------------- GEMM: C[M,N] = A[M,K] * B[N,K]^T, bf16 inputs ----------------
// EPI 3: bf16 + bias + GELU    EPI 4: f32 partial (split-K over gridDim.z)
template <int EPI>
__global__ __launch_bounds__(256, 2) void k_gemm(const u16* __restrict__ A,
                                                 const u16* __restrict__ B,
                                                 void* __restrict__ out,
                                                 const float* __restrict__ bias,
                                                 int M, int N, int K) {
  __shared__ __attribute__((aligned(16))) u16 As[128 * 32];
  __shared__ __attribute__((aligned(16))) u16 Bs[128 * 32];
  const int t = threadIdx.x;
  const int w = t >> 6, l = t & 63, g = l >> 4, c = l & 15;
  const int wr = w >> 1, wc = w & 1;
  const int bm = blockIdx.y, bn = blockIdx.x;

  f32x4 acc[4][4] = {};
  int nk = K >> 5, kk0 = 0;
  if (EPI == 4) { nk = nk / gridDim.z; kk0 = blockIdx.z * nk; }

  const int srow = t >> 2;
  const int sj = t & 3;
  const char* Abase = (const char*)A;
  const char* Bbase = (const char*)B;

  for (int kk = kk0; kk < kk0 + nk; ++kk) {
    const size_t kb = (size_t)kk * 64;
    uint4 a0 = *(const uint4*)(Abase + ((size_t)(bm * 128 + srow) * K) * 2 + kb + sj * 16);
    uint4 a1 = *(const uint4*)(Abase + ((size_t)(bm * 128 + srow + 64) * K) * 2 + kb + sj * 16);
    uint4 b0 = *(const uint4*)(Bbase + ((size_t)(bn * 128 + srow) * K) * 2 + kb + sj * 16);
    uint4 b1 = *(const uint4*)(Bbase + ((size_t)(bn * 128 + srow + 64) * K) * 2 + kb + sj * 16);
    __syncthreads();
    const int sw0 = (sj * 16) ^ (((srow >> 1) & 3) << 4);
    const int sw1 = (sj * 16) ^ ((((srow + 64) >> 1) & 3) << 4);
    *(uint4*)((char*)As + srow * 64 + sw0) = a0;
    *(uint4*)((char*)As + (srow + 64) * 64 + sw1) = a1;
    *(uint4*)((char*)Bs + srow * 64 + sw0) = b0;
    *(uint4*)((char*)Bs + (srow + 64) * 64 + sw1) = b1;
    __syncthreads();
    short8 af[4], bfr[4];
#pragma unroll
    for (int m = 0; m < 4; ++m) {
      int row = wr * 64 + m * 16 + c;
      af[m] = ldfrag((const char*)As + row * 64 + ((g * 16) ^ (((row >> 1) & 3) << 4)));
    }
#pragma unroll
    for (int n = 0; n < 4; ++n) {
      int row = wc * 64 + n * 16 + c;
      bfr[n] = ldfrag((const char*)Bs + row * 64 + ((g * 16) ^ (((row >> 1) & 3) << 4)));
    }
#pragma unroll
    for (int m = 0; m < 4; ++m)
#pragma unroll
      for (int n = 0; n < 4; ++n) acc[m][n] = MFMA16(af[m], bfr[n], acc[m][n]);
  }

  const int row0 = bm * 128 + wr * 64 + 4 * g;
  const int col0 = bn * 128 + wc * 64 + c;
#pragma unroll
  for (int m = 0; m < 4; ++m) {
#pragma unroll
    for (int n = 0; n < 4; ++n) {
      const int row = row0 + m * 16;
      const int col = col0 + n * 16;
      if (EPI == 3) {
        float bc = bias[col];
#pragma unroll
        for (int rr = 0; rr < 4; ++rr)
          ((u16*)out)[(size_t)(row + rr) * N + col] = f2b(gelu_exact(acc[m][n][rr] + bc));
      } else {
        float* po = (float*)out + (size_t)blockIdx.z * M * N;
#pragma unroll
        for (int rr = 0; rr < 4; ++rr)
          po[(size_t)(row + rr) * N + col] = acc[m][n][rr];
      }
    }
  }
}

// ---------------- Wo GEMM with fused kv-split merge in A-staging ----------------
__global__ __launch_bounds__(256, 2) void k_gemm_wo(const u16* __restrict__ part,
                                                    const float* __restrict__ ml,
                                                    const u16* __restrict__ B,
                                                    float* __restrict__ out) {
  constexpr int M = 4096, N = 256, K = 2048;
  __shared__ __attribute__((aligned(16))) u16 As[128 * 32];
  __shared__ __attribute__((aligned(16))) u16 Bs[128 * 32];
  const int t = threadIdx.x;
  const int w = t >> 6, l = t & 63, g = l >> 4, c = l & 15;
  const int wr = w >> 1, wc = w & 1;
  const int bm = blockIdx.y, bn = blockIdx.x;
  const int nk = 16, kk0 = blockIdx.z * 16;
  const int h0 = kk0 >> 3;
  const float C2 = 0.0625f * 1.44269504f;

  const int srow = t >> 2;
  const int sj = t & 3;
  const int r0 = bm * 128 + srow, r1 = r0 + 64;

  float wgt[8];
#pragma unroll
  for (int rr = 0; rr < 2; ++rr) {
    const int row = rr ? r1 : r0;
#pragma unroll
    for (int hh = 0; hh < 2; ++hh) {
      const int h = h0 + hh;
      float m0 = ml[(0 + h) * 4096 + row];
      float l0 = ml[(8 + h) * 4096 + row];
      float m1 = ml[(16 + h) * 4096 + row];
      float l1 = ml[(24 + h) * 4096 + row];
      float Mx = fmaxf(m0, m1);
      float w0 = EXP2((m0 - Mx) * C2), w1 = EXP2((m1 - Mx) * C2);
      float inv = 1.0f / (l0 * w0 + l1 * w1);
      wgt[rr * 4 + hh * 2 + 0] = w0 * inv;
      wgt[rr * 4 + hh * 2 + 1] = w1 * inv;
    }
  }

  f32x4 acc[4][4] = {};
  const char* Pbase = (const char*)part;
  const char* Bbase = (const char*)B;
  const size_t PSTRIDE = (size_t)4096 * 2048 * 2;

  for (int kk = kk0; kk < kk0 + nk; ++kk) {
    const int hh = (kk >> 3) & 1;
    const size_t kb = (size_t)kk * 64;
    const size_t a0off = ((size_t)r0 * K) * 2 + kb + sj * 16;
    const size_t a1off = ((size_t)r1 * K) * 2 + kb + sj * 16;
    uint4 p00 = *(const uint4*)(Pbase + a0off);
    uint4 p01 = *(const uint4*)(Pbase + PSTRIDE + a0off);
    uint4 p10 = *(const uint4*)(Pbase + a1off);
    uint4 p11 = *(const uint4*)(Pbase + PSTRIDE + a1off);
    uint4 b0 = *(const uint4*)(Bbase + ((size_t)(bn * 128 + srow) * K) * 2 + kb + sj * 16);
    uint4 b1 = *(const uint4*)(Bbase + ((size_t)(bn * 128 + srow + 64) * K) * 2 + kb + sj * 16);

    float w00 = hh ? wgt[2] : wgt[0], w01 = hh ? wgt[3] : wgt[1];
    float w10 = hh ? wgt[6] : wgt[4], w11 = hh ? wgt[7] : wgt[5];
    uint4 a0, a1;
    {
      const u16* x0 = (const u16*)&p00;
      const u16* x1 = (const u16*)&p01;
      u16* o = (u16*)&a0;
#pragma unroll
      for (int j = 0; j < 8; ++j) o[j] = f2b(b2f(x0[j]) * w00 + b2f(x1[j]) * w01);
      const u16* y0 = (const u16*)&p10;
      const u16* y1 = (const u16*)&p11;
      u16* o1 = (u16*)&a1;
#pragma unroll
      for (int j = 0; j < 8; ++j) o1[j] = f2b(b2f(y0[j]) * w10 + b2f(y1[j]) * w11);
    }

    __syncthreads();
    const int sw0 = (sj * 16) ^ (((srow >> 1) & 3) << 4);
    const int sw1 = (sj * 16) ^ ((((srow + 64) >> 1) & 3) << 4);
    *(uint4*)((char*)As + srow * 64 + sw0) = a0;
    *(uint4*)((char*)As + (srow + 64) * 64 + sw1) = a1;
    *(uint4*)((char*)Bs + srow * 64 + sw0) = b0;
    *(uint4*)((char*)Bs + (srow + 64) * 64 + sw1) = b1;
    __syncthreads();
    short8 af[4], bfr[4];
#pragma unroll
    for (int m = 0; m < 4; ++m) {
      int row = wr * 64 + m * 16 + c;
      af[m] = ldfrag((const char*)As + row * 64 + ((g * 16) ^ (((row >> 1) & 3) << 4)));
    }
#pragma unroll
    for (int n = 0; n < 4; ++n) {
      int row = wc * 64 + n * 16 + c;
      bfr[n] = ldfrag((const char*)Bs + row * 64 + ((g * 16) ^ (((row >> 1) & 3) << 4)));
    }
#pragma unroll
    for (int m = 0; m < 4; ++m)
#pragma unroll
      for (int n = 0; n < 4; ++n) acc[m][n] = MFMA16(af[m], bfr[n], acc[m][n]);
  }

  const int row0 = bm * 128 + wr * 64 + 4 * g;
  const int col0 = bn * 128 + wc * 64 + c;
  float* po = out + (size_t)blockIdx.z * M * N;
#pragma unroll
  for (int m = 0; m < 4; ++m)
#pragma unroll
    for (int n = 0; n < 4; ++n)
#pragma unroll
      for (int rr = 0; rr < 4; ++rr)
        po[(size_t)(row0 + m * 16 + rr) * N + col0 + n * 16] = acc[m][n][rr];
}

// ---------------- merged QKV GEMM: Q,K -> fp8 sigma-layout; V -> bf16 transposed ----------------
__global__ __launch_bounds__(256, 2) void k_gemm_qkv(const u16* __restrict__ A,
                                                     const u16* __restrict__ Bq,
                                                     const u16* __restrict__ Bk,
                                                     const u16* __restrict__ Bv,
                                                     u8* __restrict__ Oq,
                                                     u8* __restrict__ Ok,
                                                     u16* __restrict__ Ov) {
  constexpr int M = 4096, N = 2048, K = 256;
  __shared__ __attribute__((aligned(16))) u16 As[128 * 32];
  __shared__ __attribute__((aligned(16))) u16 Bs[128 * 32];
  const int t = threadIdx.x;
  const int w = t >> 6, l = t & 63, g = l >> 4, c = l & 15;
  const int wr = w >> 1, wc = w & 1;
  const int sel = blockIdx.x >> 4;
  const int bn = blockIdx.x & 15;
  const int bm = blockIdx.y;
  const u16* B = sel == 0 ? Bq : (sel == 1 ? Bk : Bv);

  f32x4 acc[4][4] = {};
  const int srow = t >> 2;
  const int sj = t & 3;
  const char* Abase = (const char*)A;
  const char* Bbase = (const char*)B;

  for (int kk = 0; kk < 8; ++kk) {
    const size_t kb = (size_t)kk * 64;
    uint4 a0 = *(const uint4*)(Abase + ((size_t)(bm * 128 + srow) * K) * 2 + kb + sj * 16);
    uint4 a1 = *(const uint4*)(Abase + ((size_t)(bm * 128 + srow + 64) * K) * 2 + kb + sj * 16);
    uint4 b0 = *(const uint4*)(Bbase + ((size_t)(bn * 128 + srow) * K) * 2 + kb + sj * 16);
    uint4 b1 = *(const uint4*)(Bbase + ((size_t)(bn * 128 + srow + 64) * K) * 2 + kb + sj * 16);
    __syncthreads();
    const int sw0 = (sj * 16) ^ (((srow >> 1) & 3) << 4);
    const int sw1 = (sj * 16) ^ ((((srow + 64) >> 1) & 3) << 4);
    *(uint4*)((char*)As + srow * 64 + sw0) = a0;
    *(uint4*)((char*)As + (srow + 64) * 64 + sw1) = a1;
    *(uint4*)((char*)Bs + srow * 64 + sw0) = b0;
    *(uint4*)((char*)Bs + (srow + 64) * 64 + sw1) = b1;
    __syncthreads();
    short8 af[4], bfr[4];
#pragma unroll
    for (int m = 0; m < 4; ++m) {
      int row = wr * 64 + m * 16 + c;
      af[m] = ldfrag((const char*)As + row * 64 + ((g * 16) ^ (((row >> 1) & 3) << 4)));
    }
#pragma unroll
    for (int n = 0; n < 4; ++n) {
      int row = wc * 64 + n * 16 + c;
      bfr[n] = ldfrag((const char*)Bs + row * 64 + ((g * 16) ^ (((row >> 1) & 3) << 4)));
    }
#pragma unroll
    for (int m = 0; m < 4; ++m)
#pragma unroll
      for (int n = 0; n < 4; ++n) acc[m][n] = MFMA16(af[m], bfr[n], acc[m][n]);
  }

  const int row0 = bm * 128 + wr * 64 + 4 * g;
  const int col0 = bn * 128 + wc * 64 + c;
  if (sel < 2) {
    u8* out = sel ? Ok : Oq;
#pragma unroll
    for (int m = 0; m < 4; ++m) {
#pragma unroll
      for (int n = 0; n < 4; ++n) {
        const int col = col0 + n * 16;
        const int d = col & 255, h = col >> 8;
        const int p = sigma(d);
        u32 lo = __builtin_amdgcn_cvt_pk_fp8_f32(acc[m][n][0], acc[m][n][1], 0, false);
        u32 hi2 = __builtin_amdgcn_cvt_pk_fp8_f32(acc[m][n][2], acc[m][n][3], 0, false);
        u32 quad = (lo & 0xffffu) | (hi2 << 16);
#pragma unroll
        for (int rr = 0; rr < 4; ++rr) {
          const int row = row0 + m * 16 + rr;
          const int byte = sel ? (((((p >> 4) ^ (row & 15)) << 4) | (p & 15))) : p;
          out[(size_t)row * 2048 + h * 256 + byte] = (u8)(quad >> (8 * rr));
        }
      }
    }
  } else {
#pragma unroll
    for (int m = 0; m < 4; ++m)
#pragma unroll
      for (int n = 0; n < 4; ++n) {
        ushort4 o = { f2b(acc[m][n][0]), f2b(acc[m][n][1]), f2b(acc[m][n][2]), f2b(acc[m][n][3]) };
        *(ushort4*)(Ov + (size_t)(col0 + n * 16) * M + row0 + m * 16) = o;
      }
  }
}

// ---------------- reduce 4 split-K partials + bias + residual -> f32 ----------------
__global__ __launch_bounds__(256) void k_red4(const float* __restrict__ p,
                                              const float* __restrict__ bias,
                                              const float* __restrict__ resid,
                                              float* __restrict__ out) {
  int i = blockIdx.x * 256 + threadIdx.x;
  const float4* p4 = (const float4*)p;
  float4 a = p4[i], b = p4[i + 262144], c = p4[i + 524288], d = p4[i + 786432];
  float4 r = ((const float4*)resid)[i];
  float4 bb = ((const float4*)bias)[i & 63];
  float4 o;
  o.x = a.x + b.x + c.x + d.x + r.x + bb.x;
  o.y = a.y + b.y + c.y + d.y + r.y + bb.y;
  o.z = a.z + b.z + c.z + d.z + r.z + bb.z;
  o.w = a.w + b.w + c.w + d.w + r.w + bb.w;
  ((float4*)out)[i] = o;
}

// ---------------- fused: reduce 4 partials + bias + resid -> x2, then LN -> bf16 ----------------
__global__ __launch_bounds__(256) void k_red4ln(const float* __restrict__ p,
                                                const float* __restrict__ bias,
                                                const float* __restrict__ resid,
                                                const float* __restrict__ g,
                                                const float* __restrict__ b,
                                                float* __restrict__ x2,
                                                u16* __restrict__ out) {
  int row = blockIdx.x * 4 + (threadIdx.x >> 6);
  int l = threadIdx.x & 63;
  int i = row * 64 + l;
  const float4* p4 = (const float4*)p;
  float4 a = p4[i], bq = p4[i + 262144], cq = p4[i + 524288], dq = p4[i + 786432];
  float4 r = ((const float4*)resid)[i];
  float4 bi = ((const float4*)bias)[l];
  float4 v;
  v.x = a.x + bq.x + cq.x + dq.x + r.x + bi.x;
  v.y = a.y + bq.y + cq.y + dq.y + r.y + bi.y;
  v.z = a.z + bq.z + cq.z + dq.z + r.z + bi.z;
  v.w = a.w + bq.w + cq.w + dq.w + r.w + bi.w;
  ((float4*)x2)[i] = v;
  float s = v.x + v.y + v.z + v.w;
#pragma unroll
  for (int m = 1; m < 64; m <<= 1) s += __shfl_xor(s, m);
  float mu = s * (1.0f / 256.0f);
  float dx = v.x - mu, dy = v.y - mu, dz = v.z - mu, dw = v.w - mu;
  float q = dx * dx + dy * dy + dz * dz + dw * dw;
#pragma unroll
  for (int m = 1; m < 64; m <<= 1) q += __shfl_xor(q, m);
  float rr = rsqrtf(q * (1.0f / 256.0f) + 1e-5f);
  float4 gv = *(const float4*)(g + l * 4);
  float4 bv = *(const float4*)(b + l * 4);
  ushort4 o = { f2b(dx * rr * gv.x + bv.x), f2b(dy * rr * gv.y + bv.y),
                f2b(dz * rr * gv.z + bv.z), f2b(dw * rr * gv.w + bv.w) };
  *(ushort4*)(out + (size_t)row * 256 + l * 4) = o;
}

// ---------------- Flash attention (kv-split-2), fp8 QK^T: 8 heads, d_head=256, N=4096 ----------------
// 4 waves x 32 q, KVBLK=32. LDS 48KB: K fp8 dbuf 2x8KB + V bf16 dbuf 2x16KB. 2 blocks/CU.
// QK^T: mfma_f32_32x32x16_fp8_fp8, dual accumulator chains. PV: bf16 (unchanged).
__global__ __launch_bounds__(256, 2) void k_attn(const u8* __restrict__ Q8,
                                                 const u8* __restrict__ K8,
                                                 const u16* __restrict__ VT,
                                                 u16* __restrict__ part,
                                                 float* __restrict__ ml) {
  __shared__ __attribute__((aligned(16))) char smem[49152];
  const int t = threadIdx.x;
  const int w = t >> 6, l = t & 63;
  const int q31 = l & 31, hi = l >> 5;
  const int head = blockIdx.x, qb = blockIdx.y, sp = blockIdx.z;
  const int kvbase = sp * 2048;
  const float C2 = 0.0625f * 1.44269504f;  // 1/sqrt(256) * log2(e)

  // Q frags: 8 x uint4; qf[g].xy = B-frag for mfma 2g, .zw = mfma 2g+1 (sigma layout)
  uint4 qf[8];
  {
    const u8* qp = Q8 + (size_t)(qb * 128 + w * 32 + q31) * 2048 + head * 256 + hi * 16;
#pragma unroll
    for (int g = 0; g < 8; ++g) qf[g] = *(const uint4*)(qp + g * 32);
  }

  f32x16 o[8] = {};
  float m = -1e30f, lsum = 0.0f;

  const u8* KbaseH = K8 + head * 256;
  const char* VbaseH = (const char*)VT + (size_t)head * 256 * 8192;

  auto stage = [&](int c) {
    const int buf = c & 1;
    const int kv0 = kvbase + c * 32;
    char* kd = smem + buf * 8192;
    char* vd = smem + 16384 + buf * 16384;
#pragma unroll
    for (int ii = 0; ii < 2; ++ii) {
      const int inst = w * 2 + ii;               // 0..7, each stages 4 rows of 256B
      const int row = inst * 4 + (l >> 4);
      llds16(KbaseH + (size_t)(kv0 + row) * 2048 + ((l & 15) << 4), kd + inst * 1024);
    }
#pragma unroll
    for (int ii = 0; ii < 4; ++ii) {
      const int row = w * 64 + ii * 16 + (l >> 2);
      llds16(VbaseH + (size_t)row * 8192 + (size_t)kv0 * 2 + (((l & 3) ^ ((row >> 3) & 3)) << 4),
             vd + (w * 4 + ii) * 1024);
    }
  };

  stage(0);
  for (int c = 0; c < 64; ++c) {
    asm volatile("s_waitcnt vmcnt(0)" ::: "memory");
    __builtin_amdgcn_s_barrier();
    __builtin_amdgcn_sched_barrier(0);
    if (c < 63) stage(c + 1);

    const char* kd = smem + (c & 1) * 8192;
    const char* vd = smem + 16384 + (c & 1) * 16384;

    // S^T = K . Q^T : C[kv][q], fp8, two accumulator chains (even/odd mfma)
    f32x16 sA = {}, sB = {};
    const char* ka = kd + q31 * 256;
    const int rsw = q31 & 15;
    __builtin_amdgcn_s_setprio(1);
#pragma unroll
    for (int g = 0; g < 8; ++g) {
      const int chunk = (g * 2 + hi) ^ rsw;
      uint4 kk = *(const uint4*)(ka + chunk * 16);
      long a0 = __builtin_bit_cast(long, (u32x2){ kk.x, kk.y });
      long a1 = __builtin_bit_cast(long, (u32x2){ kk.z, kk.w });
      long q0 = __builtin_bit_cast(long, (u32x2){ qf[g].x, qf[g].y });
      long q1 = __builtin_bit_cast(long, (u32x2){ qf[g].z, qf[g].w });
      sA = MFMA8(a0, q0, sA);
      sB = MFMA8(a1, q1, sB);
    }
    __builtin_amdgcn_s_setprio(0);
    f32x16 s = sA + sB;

    // online softmax (kv lane-local), tree reductions, defer-max
    float m8[8];
#pragma unroll
    for (int i = 0; i < 8; ++i) m8[i] = fmaxf(s[i], s[i + 8]);
#pragma unroll
    for (int i = 0; i < 4; ++i) m8[i] = fmaxf(m8[i], m8[i + 4]);
    float pm = fmaxf(fmaxf(m8[0], m8[1]), fmaxf(m8[2], m8[3]));
    pm = fmaxf(pm, __shfl_xor(pm, 32));
    if (__any(pm > m + 64.0f)) {
      float mn = fmaxf(m, pm);
      float sc = EXP2((m - mn) * C2);
      m = mn;
      lsum *= sc;
#pragma unroll
      for (int i = 0; i < 16; ++i) {
        const int r = (i & 3) + 8 * (i >> 2) + 4 * hi;
        float sclr = __shfl(sc, r);
#pragma unroll
        for (int dt = 0; dt < 8; ++dt) o[dt][i] *= sclr;
      }
    }
    const float mc2 = m * C2;
    float p[16];
#pragma unroll
    for (int i = 0; i < 16; ++i) p[i] = EXP2(fmaf(s[i], C2, -mc2));
    float r8[8];
#pragma unroll
    for (int i = 0; i < 8; ++i) r8[i] = p[i] + p[i + 8];
#pragma unroll
    for (int i = 0; i < 4; ++i) r8[i] += r8[i + 4];
    float rs = (r8[0] + r8[1]) + (r8[2] + r8[3]);
    rs += __shfl_xor(rs, 32);
    lsum += rs;

    // in-register P (bf16) -> A-fragments via cvt_pk + permlane32_swap
    u32 pk[8];
#pragma unroll
    for (int j = 0; j < 8; ++j)
      asm("v_cvt_pk_bf16_f32 %0, %1, %2" : "=v"(pk[j]) : "v"(p[2 * j]), "v"(p[2 * j + 1]));
    asm("v_permlane32_swap_b32 %0, %1" : "+v"(pk[0]), "+v"(pk[2]));
    asm("v_permlane32_swap_b32 %0, %1" : "+v"(pk[1]), "+v"(pk[3]));
    asm("v_permlane32_swap_b32 %0, %1" : "+v"(pk[4]), "+v"(pk[6]));
    asm("v_permlane32_swap_b32 %0, %1" : "+v"(pk[5]), "+v"(pk[7]));
    uint4 f0 = { pk[0], pk[1], pk[2], pk[3] };
    uint4 f1 = { pk[4], pk[5], pk[6], pk[7] };
    short8 pa0 = __builtin_bit_cast(short8, f0);
    short8 pa1 = __builtin_bit_cast(short8, f1);

    // O += P . V : B=V[kv][32d] bf16 from LDS
    __builtin_amdgcn_s_setprio(1);
#pragma unroll
    for (int dt = 0; dt < 8; ++dt) {
      const int row = dt * 32 + q31;
      const char* vr = vd + row * 64;
      const int vs = ((row >> 3) & 3) << 4;
      short8 b0 = ldfrag(vr + ((hi * 16) ^ vs));
      short8 b1 = ldfrag(vr + ((32 + hi * 16) ^ vs));
      o[dt] = MFMA32(pa0, b0, o[dt]);
      o[dt] = MFMA32(pa1, b1, o[dt]);
    }
    __builtin_amdgcn_s_setprio(0);
  }

  u16* pb = part + (size_t)sp * 4096 * 2048;
#pragma unroll
  for (int i = 0; i < 16; ++i) {
    const int r = (i & 3) + 8 * (i >> 2) + 4 * hi;
    const size_t qg = (size_t)(qb * 128 + w * 32 + r);
#pragma unroll
    for (int dt = 0; dt < 8; ++dt)
      pb[qg * 2048 + head * 256 + dt * 32 + q31] = f2b(o[dt][i]);
  }
  if (hi == 0) {
    const int qg = qb * 128 + w * 32 + q31;
    ml[((sp * 2 + 0) * 8 + head) * 4096 + qg] = m;
    ml[((sp * 2 + 1) * 8 + head) * 4096 + qg] = lsum;
  }
}

// ---------------- launch ----------------
extern "C" void kernel_launch(void* const* d_in, const int* in_sizes, int n_in,
                              void* d_out, int out_size, void* d_ws, size_t ws_size,
                              hipStream_t stream) {
  const float* x   = (const float*)d_in[0];
  const float* Wq  = (const float*)d_in[1];
  const float* Wk  = (const float*)d_in[2];
  const float* Wv  = (const float*)d_in[3];
  const float* Wo  = (const float*)d_in[4];
  const float* bo  = (const float*)d_in[5];
  const float* g1  = (const float*)d_in[6];
  const float* be1 = (const float*)d_in[7];
  const float* g2  = (const float*)d_in[8];
  const float* be2 = (const float*)d_in[9];
  const float* W1  = (const float*)d_in[10];
  const float* b1  = (const float*)d_in[11];
  const float* W2  = (const float*)d_in[12];
  const float* b2  = (const float*)d_in[13];

  char* ws = (char*)d_ws;
  size_t off = 0;
  auto alloc = [&](size_t n) {
    char* p = ws + off;
    off = (off + n + 255) & ~(size_t)255;
    return p;
  };
  u16* hb    = (u16*)alloc(4096 * 256 * 2);
  u16* Wqb   = (u16*)alloc(2048 * 256 * 2);
  u16* Wkb   = (u16*)alloc(2048 * 256 * 2);
  u16* Wvb   = (u16*)alloc(2048 * 256 * 2);
  u16* Wob   = (u16*)alloc(256 * 2048 * 2);
  u16* W1b   = (u16*)alloc(1024 * 256 * 2);
  u16* W2b   = (u16*)alloc(256 * 1024 * 2);
  u8*  Qb8   = (u8*)alloc((size_t)4096 * 2048);      // fp8 sigma-layout
  u8*  Kb8   = (u8*)alloc((size_t)4096 * 2048);      // fp8 sigma-layout, row-swizzled
  u16* VTb   = (u16*)alloc((size_t)2048 * 4096 * 2);
  u16* attnb = (u16*)alloc((size_t)2 * 4096 * 2048 * 2);  // 2 kv-split partials (merged in Wo GEMM)
  float* mlb = (float*)alloc(32 * 4096 * 4);
  float* x2  = (float*)alloc(4096 * 256 * 4);
  u16* h2b   = (u16*)alloc(4096 * 256 * 2);
  u16* ffn1  = (u16*)alloc((size_t)4096 * 1024 * 2);
  float* pbuf = (float*)Qb8;  // Qb8+Kb8 = 16MB contiguous, dead after k_attn: 4x [4096][256] f32

  k_prep<<<dim3(1024, 7), 256, 0, stream>>>(Wq, Wk, Wv, Wo, W1, W2,
                                            Wqb, Wkb, Wvb, Wob, W1b, W2b,
                                            x, g1, be1, hb);

  k_gemm_qkv<<<dim3(48, 32), 256, 0, stream>>>(hb, Wqb, Wkb, Wvb, Qb8, Kb8, VTb);

  k_attn<<<dim3(8, 32, 2), 256, 0, stream>>>(Qb8, Kb8, VTb, attnb, mlb);

  k_gemm_wo<<<dim3(2, 32, 4), 256, 0, stream>>>(attnb, mlb, Wob, pbuf);
  k_red4ln<<<1024, 256, 0, stream>>>(pbuf, bo, x, g2, be2, x2, h2b);
  k_gemm<3><<<dim3(8, 32), 256, 0, stream>>>(h2b, W1b, ffn1, b1, 4096, 1024, 256);
  k_gemm<4><<<dim3(2, 32, 4), 256, 0, stream>>>(ffn1, W2b, pbuf, nullptr, 4096, 256, 1024);
  k_red4<<<1024, 256, 0, stream>>>(pbuf, b2, x2, (float*)d_out);
}

// Round 9
// 214.212 us; speedup vs baseline: 1.5014x; 1.0014x over previous
//
#include <hip/hip_runtime.h>

typedef __attribute__((ext_vector_type(8))) short short8;
typedef __attribute__((ext_vector_type(4))) float f32x4;
typedef __attribute__((ext_vector_type(16))) float f32x16;
typedef __attribute__((ext_vector_type(2))) unsigned int u32x2;
typedef unsigned short u16;
typedef unsigned int u32;
typedef unsigned char u8;

#define DEVFN static __device__ __forceinline__

DEVFN u16 f2b(float f) {
  u32 u = __builtin_bit_cast(u32, f);
  u32 r = u + 0x7fffu + ((u >> 16) & 1u);
  return (u16)(r >> 16);
}

DEVFN float b2f(u16 b) {
  u32 u = ((u32)b) << 16;
  return __builtin_bit_cast(float, u);
}

DEVFN short8 ldfrag(const void* p) {
  return __builtin_bit_cast(short8, *(const uint4*)p);
}

#define MFMA16(a, b, c) __builtin_amdgcn_mfma_f32_16x16x32_bf16((a), (b), (c), 0, 0, 0)
#define MFMA32(a, b, c) __builtin_amdgcn_mfma_f32_32x32x16_bf16((a), (b), (c), 0, 0, 0)
#define MFMA8(a, b, c) __builtin_amdgcn_mfma_f32_32x32x16_fp8_fp8((a), (b), (c), 0, 0, 0)
#define EXP2(x) __builtin_amdgcn_exp2f(x)

DEVFN void llds16(const void* g, void* l) {
  __builtin_amdgcn_global_load_lds((const __attribute__((address_space(1))) void*)g,
                                   (__attribute__((address_space(3))) void*)l, 16, 0, 0);
}

DEVFN float gelu_exact(float v) {
  return 0.5f * v * (1.0f + erff(v * 0.70710678118654752f));
}

// sigma: swap bits 3 and 4 (involution) — interleave so one 16B read feeds 2 fp8 MFMA frags
DEVFN int sigma(int d) {
  return (d & ~24) | ((d & 8) << 1) | ((d & 16) >> 1);
}

// ---------------- fused: weight f32->bf16 (y<6) + LayerNorm1 (y==6) ----------------
__global__ __launch_bounds__(256) void k_prep(const float* s0, const float* s1, const float* s2,
                                              const float* s3, const float* s4, const float* s5,
                                              u16* d0, u16* d1, u16* d2, u16* d3, u16* d4, u16* d5,
                                              const float* x, const float* g1, const float* be1,
                                              u16* hb) {
  const int y = blockIdx.y;
  if (y < 6) {
    int i = blockIdx.x * 256 + threadIdx.x;
    const float* s;
    u16* d;
    int n4;
    switch (y) {
      case 0: s = s0; d = d0; n4 = 131072; break;
      case 1: s = s1; d = d1; n4 = 131072; break;
      case 2: s = s2; d = d2; n4 = 131072; break;
      case 3: s = s3; d = d3; n4 = 131072; break;
      case 4: s = s4; d = d4; n4 = 65536; break;
      default: s = s5; d = d5; n4 = 65536; break;
    }
    if (i >= n4) return;
    float4 v = ((const float4*)s)[i];
    ushort4 o = { f2b(v.x), f2b(v.y), f2b(v.z), f2b(v.w) };
    ((ushort4*)d)[i] = o;
    return;
  }
  int row = blockIdx.x * 4 + (threadIdx.x >> 6);
  int l = threadIdx.x & 63;
  const float4 v = *(const float4*)(x + (size_t)row * 256 + l * 4);
  float s = v.x + v.y + v.z + v.w;
#pragma unroll
  for (int m = 1; m < 64; m <<= 1) s += __shfl_xor(s, m);
  float mu = s * (1.0f / 256.0f);
  float dx = v.x - mu, dy = v.y - mu, dz = v.z - mu, dw = v.w - mu;
  float q = dx * dx + dy * dy + dz * dz + dw * dw;
#pragma unroll
  for (int m = 1; m < 64; m <<= 1) q += __shfl_xor(q, m);
  float r = rsqrtf(q * (1.0f / 256.0f) + 1e-5f);
  float4 gv = *(const float4*)(g1 + l * 4);
  float4 bv = *(const float4*)(be1 + l * 4);
  ushort4 o = { f2b(dx * r * gv.x + bv.x), f2b(dy * r * gv.y + bv.y),
                f2b(dz * r * gv.z + bv.z), f2b(dw * r * gv.w + bv.w) };
  *(ushort4*)(hb + (size_t)row * 256 + l * 4) = o;
}

// ---------------- GEMM: C[M,N] = A[M,K] * B[N,K]^T, bf16 inputs ----------------
// EPI 3: bf16 + bias + GELU    EPI 4: f32 partial (split-K over gridDim.z)
template <int EPI>
__global__ __launch_bounds__(256, 2) void k_gemm(const u16* __restrict__ A,
                                                 const u16* __restrict__ B,
                                                 void* __restrict__ out,
                                                 const float* __restrict__ bias,
                                                 int M, int N, int K) {
  __shared__ __attribute__((aligned(16))) u16 As[128 * 32];
  __shared__ __attribute__((aligned(16))) u16 Bs[128 * 32];
  const int t = threadIdx.x;
  const int w = t >> 6, l = t & 63, g = l >> 4, c = l & 15;
  const int wr = w >> 1, wc = w & 1;
  const int bm = blockIdx.y, bn = blockIdx.x;

  f32x4 acc[4][4] = {};
  int nk = K >> 5, kk0 = 0;
  if (EPI == 4) { nk = nk / gridDim.z; kk0 = blockIdx.z * nk; }

  const int srow = t >> 2;
  const int sj = t & 3;
  const char* Abase = (const char*)A;
  const char* Bbase = (const char*)B;

  for (int kk = kk0; kk < kk0 + nk; ++kk) {
    const size_t kb = (size_t)kk * 64;
    uint4 a0 = *(const uint4*)(Abase + ((size_t)(bm * 128 + srow) * K) * 2 + kb + sj * 16);
    uint4 a1 = *(const uint4*)(Abase + ((size_t)(bm * 128 + srow + 64) * K) * 2 + kb + sj * 16);
    uint4 b0 = *(const uint4*)(Bbase + ((size_t)(bn * 128 + srow) * K) * 2 + kb + sj * 16);
    uint4 b1 = *(const uint4*)(Bbase + ((size_t)(bn * 128 + srow + 64) * K) * 2 + kb + sj * 16);
    __syncthreads();
    const int sw0 = (sj * 16) ^ (((srow >> 1) & 3) << 4);
    const int sw1 = (sj * 16) ^ ((((srow + 64) >> 1) & 3) << 4);
    *(uint4*)((char*)As + srow * 64 + sw0) = a0;
    *(uint4*)((char*)As + (srow + 64) * 64 + sw1) = a1;
    *(uint4*)((char*)Bs + srow * 64 + sw0) = b0;
    *(uint4*)((char*)Bs + (srow + 64) * 64 + sw1) = b1;
    __syncthreads();
    short8 af[4], bfr[4];
#pragma unroll
    for (int m = 0; m < 4; ++m) {
      int row = wr * 64 + m * 16 + c;
      af[m] = ldfrag((const char*)As + row * 64 + ((g * 16) ^ (((row >> 1) & 3) << 4)));
    }
#pragma unroll
    for (int n = 0; n < 4; ++n) {
      int row = wc * 64 + n * 16 + c;
      bfr[n] = ldfrag((const char*)Bs + row * 64 + ((g * 16) ^ (((row >> 1) & 3) << 4)));
    }
#pragma unroll
    for (int m = 0; m < 4; ++m)
#pragma unroll
      for (int n = 0; n < 4; ++n) acc[m][n] = MFMA16(af[m], bfr[n], acc[m][n]);
  }

  const int row0 = bm * 128 + wr * 64 + 4 * g;
  const int col0 = bn * 128 + wc * 64 + c;
#pragma unroll
  for (int m = 0; m < 4; ++m) {
#pragma unroll
    for (int n = 0; n < 4; ++n) {
      const int row = row0 + m * 16;
      const int col = col0 + n * 16;
      if (EPI == 3) {
        float bc = bias[col];
#pragma unroll
        for (int rr = 0; rr < 4; ++rr)
          ((u16*)out)[(size_t)(row + rr) * N + col] = f2b(gelu_exact(acc[m][n][rr] + bc));
      } else {
        float* po = (float*)out + (size_t)blockIdx.z * M * N;
#pragma unroll
        for (int rr = 0; rr < 4; ++rr)
          po[(size_t)(row + rr) * N + col] = acc[m][n][rr];
      }
    }
  }
}

// ---------------- Wo GEMM with fused kv-split merge in A-staging ----------------
__global__ __launch_bounds__(256, 2) void k_gemm_wo(const u16* __restrict__ part,
                                                    const float* __restrict__ ml,
                                                    const u16* __restrict__ B,
                                                    float* __restrict__ out) {
  constexpr int M = 4096, N = 256, K = 2048;
  __shared__ __attribute__((aligned(16))) u16 As[128 * 32];
  __shared__ __attribute__((aligned(16))) u16 Bs[128 * 32];
  const int t = threadIdx.x;
  const int w = t >> 6, l = t & 63, g = l >> 4, c = l & 15;
  const int wr = w >> 1, wc = w & 1;
  const int bm = blockIdx.y, bn = blockIdx.x;
  const int nk = 16, kk0 = blockIdx.z * 16;
  const int h0 = kk0 >> 3;
  const float C2 = 0.0625f * 1.44269504f;

  const int srow = t >> 2;
  const int sj = t & 3;
  const int r0 = bm * 128 + srow, r1 = r0 + 64;

  float wgt[8];
#pragma unroll
  for (int rr = 0; rr < 2; ++rr) {
    const int row = rr ? r1 : r0;
#pragma unroll
    for (int hh = 0; hh < 2; ++hh) {
      const int h = h0 + hh;
      float m0 = ml[(0 + h) * 4096 + row];
      float l0 = ml[(8 + h) * 4096 + row];
      float m1 = ml[(16 + h) * 4096 + row];
      float l1 = ml[(24 + h) * 4096 + row];
      float Mx = fmaxf(m0, m1);
      float w0 = EXP2((m0 - Mx) * C2), w1 = EXP2((m1 - Mx) * C2);
      float inv = 1.0f / (l0 * w0 + l1 * w1);
      wgt[rr * 4 + hh * 2 + 0] = w0 * inv;
      wgt[rr * 4 + hh * 2 + 1] = w1 * inv;
    }
  }

  f32x4 acc[4][4] = {};
  const char* Pbase = (const char*)part;
  const char* Bbase = (const char*)B;
  const size_t PSTRIDE = (size_t)4096 * 2048 * 2;

  for (int kk = kk0; kk < kk0 + nk; ++kk) {
    const int hh = (kk >> 3) & 1;
    const size_t kb = (size_t)kk * 64;
    const size_t a0off = ((size_t)r0 * K) * 2 + kb + sj * 16;
    const size_t a1off = ((size_t)r1 * K) * 2 + kb + sj * 16;
    uint4 p00 = *(const uint4*)(Pbase + a0off);
    uint4 p01 = *(const uint4*)(Pbase + PSTRIDE + a0off);
    uint4 p10 = *(const uint4*)(Pbase + a1off);
    uint4 p11 = *(const uint4*)(Pbase + PSTRIDE + a1off);
    uint4 b0 = *(const uint4*)(Bbase + ((size_t)(bn * 128 + srow) * K) * 2 + kb + sj * 16);
    uint4 b1 = *(const uint4*)(Bbase + ((size_t)(bn * 128 + srow + 64) * K) * 2 + kb + sj * 16);

    float w00 = hh ? wgt[2] : wgt[0], w01 = hh ? wgt[3] : wgt[1];
    float w10 = hh ? wgt[6] : wgt[4], w11 = hh ? wgt[7] : wgt[5];
    uint4 a0, a1;
    {
      const u16* x0 = (const u16*)&p00;
      const u16* x1 = (const u16*)&p01;
      u16* o = (u16*)&a0;
#pragma unroll
      for (int j = 0; j < 8; ++j) o[j] = f2b(b2f(x0[j]) * w00 + b2f(x1[j]) * w01);
      const u16* y0 = (const u16*)&p10;
      const u16* y1 = (const u16*)&p11;
      u16* o1 = (u16*)&a1;
#pragma unroll
      for (int j = 0; j < 8; ++j) o1[j] = f2b(b2f(y0[j]) * w10 + b2f(y1[j]) * w11);
    }

    __syncthreads();
    const int sw0 = (sj * 16) ^ (((srow >> 1) & 3) << 4);
    const int sw1 = (sj * 16) ^ ((((srow + 64) >> 1) & 3) << 4);
    *(uint4*)((char*)As + srow * 64 + sw0) = a0;
    *(uint4*)((char*)As + (srow + 64) * 64 + sw1) = a1;
    *(uint4*)((char*)Bs + srow * 64 + sw0) = b0;
    *(uint4*)((char*)Bs + (srow + 64) * 64 + sw1) = b1;
    __syncthreads();
    short8 af[4], bfr[4];
#pragma unroll
    for (int m = 0; m < 4; ++m) {
      int row = wr * 64 + m * 16 + c;
      af[m] = ldfrag((const char*)As + row * 64 + ((g * 16) ^ (((row >> 1) & 3) << 4)));
    }
#pragma unroll
    for (int n = 0; n < 4; ++n) {
      int row = wc * 64 + n * 16 + c;
      bfr[n] = ldfrag((const char*)Bs + row * 64 + ((g * 16) ^ (((row >> 1) & 3) << 4)));
    }
#pragma unroll
    for (int m = 0; m < 4; ++m)
#pragma unroll
      for (int n = 0; n < 4; ++n) acc[m][n] = MFMA16(af[m], bfr[n], acc[m][n]);
  }

  const int row0 = bm * 128 + wr * 64 + 4 * g;
  const int col0 = bn * 128 + wc * 64 + c;
  float* po = out + (size_t)blockIdx.z * M * N;
#pragma unroll
  for (int m = 0; m < 4; ++m)
#pragma unroll
    for (int n = 0; n < 4; ++n)
#pragma unroll
      for (int rr = 0; rr < 4; ++rr)
        po[(size_t)(row0 + m * 16 + rr) * N + col0 + n * 16] = acc[m][n][rr];
}

// ---------------- merged QKV GEMM: Q,K -> fp8 sigma-d-layout; V -> fp8 transposed kv-sigma ----------------
__global__ __launch_bounds__(256, 2) void k_gemm_qkv(const u16* __restrict__ A,
                                                     const u16* __restrict__ Bq,
                                                     const u16* __restrict__ Bk,
                                                     const u16* __restrict__ Bv,
                                                     u8* __restrict__ Oq,
                                                     u8* __restrict__ Ok,
                                                     u8* __restrict__ Ov8) {
  constexpr int M = 4096, N = 2048, K = 256;
  __shared__ __attribute__((aligned(16))) u16 As[128 * 32];
  __shared__ __attribute__((aligned(16))) u16 Bs[128 * 32];
  const int t = threadIdx.x;
  const int w = t >> 6, l = t & 63, g = l >> 4, c = l & 15;
  const int wr = w >> 1, wc = w & 1;
  const int sel = blockIdx.x >> 4;
  const int bn = blockIdx.x & 15;
  const int bm = blockIdx.y;
  const u16* B = sel == 0 ? Bq : (sel == 1 ? Bk : Bv);

  f32x4 acc[4][4] = {};
  const int srow = t >> 2;
  const int sj = t & 3;
  const char* Abase = (const char*)A;
  const char* Bbase = (const char*)B;

  for (int kk = 0; kk < 8; ++kk) {
    const size_t kb = (size_t)kk * 64;
    uint4 a0 = *(const uint4*)(Abase + ((size_t)(bm * 128 + srow) * K) * 2 + kb + sj * 16);
    uint4 a1 = *(const uint4*)(Abase + ((size_t)(bm * 128 + srow + 64) * K) * 2 + kb + sj * 16);
    uint4 b0 = *(const uint4*)(Bbase + ((size_t)(bn * 128 + srow) * K) * 2 + kb + sj * 16);
    uint4 b1 = *(const uint4*)(Bbase + ((size_t)(bn * 128 + srow + 64) * K) * 2 + kb + sj * 16);
    __syncthreads();
    const int sw0 = (sj * 16) ^ (((srow >> 1) & 3) << 4);
    const int sw1 = (sj * 16) ^ ((((srow + 64) >> 1) & 3) << 4);
    *(uint4*)((char*)As + srow * 64 + sw0) = a0;
    *(uint4*)((char*)As + (srow + 64) * 64 + sw1) = a1;
    *(uint4*)((char*)Bs + srow * 64 + sw0) = b0;
    *(uint4*)((char*)Bs + (srow + 64) * 64 + sw1) = b1;
    __syncthreads();
    short8 af[4], bfr[4];
#pragma unroll
    for (int m = 0; m < 4; ++m) {
      int row = wr * 64 + m * 16 + c;
      af[m] = ldfrag((const char*)As + row * 64 + ((g * 16) ^ (((row >> 1) & 3) << 4)));
    }
#pragma unroll
    for (int n = 0; n < 4; ++n) {
      int row = wc * 64 + n * 16 + c;
      bfr[n] = ldfrag((const char*)Bs + row * 64 + ((g * 16) ^ (((row >> 1) & 3) << 4)));
    }
#pragma unroll
    for (int m = 0; m < 4; ++m)
#pragma unroll
      for (int n = 0; n < 4; ++n) acc[m][n] = MFMA16(af[m], bfr[n], acc[m][n]);
  }

  const int row0 = bm * 128 + wr * 64 + 4 * g;
  const int col0 = bn * 128 + wc * 64 + c;
  if (sel < 2) {
    u8* out = sel ? Ok : Oq;
#pragma unroll
    for (int m = 0; m < 4; ++m) {
#pragma unroll
      for (int n = 0; n < 4; ++n) {
        const int col = col0 + n * 16;
        const int d = col & 255, h = col >> 8;
        const int p = sigma(d);
        u32 lo = __builtin_amdgcn_cvt_pk_fp8_f32(acc[m][n][0], acc[m][n][1], 0, false);
        u32 hi2 = __builtin_amdgcn_cvt_pk_fp8_f32(acc[m][n][2], acc[m][n][3], 0, false);
        u32 quad = (lo & 0xffffu) | (hi2 << 16);
#pragma unroll
        for (int rr = 0; rr < 4; ++rr) {
          const int row = row0 + m * 16 + rr;
          const int byte = sel ? (((((p >> 4) ^ (row & 15)) << 4) | (p & 15))) : p;
          out[(size_t)row * 2048 + h * 256 + byte] = (u8)(quad >> (8 * rr));
        }
      }
    }
  } else {
    // V -> fp8 transposed: Ov8[head][d][kv_sigma], rows = kv (4 consecutive -> one u32 store)
#pragma unroll
    for (int m = 0; m < 4; ++m)
#pragma unroll
      for (int n = 0; n < 4; ++n) {
        const int col = col0 + n * 16;
        const int d = col & 255, h = col >> 8;
        u32 q = __builtin_amdgcn_cvt_pk_fp8_f32(acc[m][n][0], acc[m][n][1], 0, false);
        q = __builtin_amdgcn_cvt_pk_fp8_f32(acc[m][n][2], acc[m][n][3], q, true);
        const int row = row0 + m * 16;  // multiple of 4; sigma swaps bits 3,4
        *(u32*)(Ov8 + (size_t)h * 1048576 + (size_t)d * 4096 + sigma(row & 31) + (row & ~31)) = q;
      }
  }
}

// ---------------- reduce 4 split-K partials + bias + residual -> f32 ----------------
__global__ __launch_bounds__(256) void k_red4(const float* __restrict__ p,
                                              const float* __restrict__ bias,
                                              const float* __restrict__ resid,
                                              float* __restrict__ out) {
  int i = blockIdx.x * 256 + threadIdx.x;
  const float4* p4 = (const float4*)p;
  float4 a = p4[i], b = p4[i + 262144], c = p4[i + 524288], d = p4[i + 786432];
  float4 r = ((const float4*)resid)[i];
  float4 bb = ((const float4*)bias)[i & 63];
  float4 o;
  o.x = a.x + b.x + c.x + d.x + r.x + bb.x;
  o.y = a.y + b.y + c.y + d.y + r.y + bb.y;
  o.z = a.z + b.z + c.z + d.z + r.z + bb.z;
  o.w = a.w + b.w + c.w + d.w + r.w + bb.w;
  ((float4*)out)[i] = o;
}

// ---------------- fused: reduce 4 partials + bias + resid -> x2, then LN -> bf16 ----------------
__global__ __launch_bounds__(256) void k_red4ln(const float* __restrict__ p,
                                                const float* __restrict__ bias,
                                                const float* __restrict__ resid,
                                                const float* __restrict__ g,
                                                const float* __restrict__ b,
                                                float* __restrict__ x2,
                                                u16* __restrict__ out) {
  int row = blockIdx.x * 4 + (threadIdx.x >> 6);
  int l = threadIdx.x & 63;
  int i = row * 64 + l;
  const float4* p4 = (const float4*)p;
  float4 a = p4[i], bq = p4[i + 262144], cq = p4[i + 524288], dq = p4[i + 786432];
  float4 r = ((const float4*)resid)[i];
  float4 bi = ((const float4*)bias)[l];
  float4 v;
  v.x = a.x + bq.x + cq.x + dq.x + r.x + bi.x;
  v.y = a.y + bq.y + cq.y + dq.y + r.y + bi.y;
  v.z = a.z + bq.z + cq.z + dq.z + r.z + bi.z;
  v.w = a.w + bq.w + cq.w + dq.w + r.w + bi.w;
  ((float4*)x2)[i] = v;
  float s = v.x + v.y + v.z + v.w;
#pragma unroll
  for (int m = 1; m < 64; m <<= 1) s += __shfl_xor(s, m);
  float mu = s * (1.0f / 256.0f);
  float dx = v.x - mu, dy = v.y - mu, dz = v.z - mu, dw = v.w - mu;
  float q = dx * dx + dy * dy + dz * dz + dw * dw;
#pragma unroll
  for (int m = 1; m < 64; m <<= 1) q += __shfl_xor(q, m);
  float rr = rsqrtf(q * (1.0f / 256.0f) + 1e-5f);
  float4 gv = *(const float4*)(g + l * 4);
  float4 bv = *(const float4*)(b + l * 4);
  ushort4 o = { f2b(dx * rr * gv.x + bv.x), f2b(dy * rr * gv.y + bv.y),
                f2b(dz * rr * gv.z + bv.z), f2b(dw * rr * gv.w + bv.w) };
  *(ushort4*)(out + (size_t)row * 256 + l * 4) = o;
}

// ---------------- Flash attention (kv-split-2), all-fp8 operands: 8 heads, d_head=256, N=4096 ----------------
// 4 waves x 32 q, KVBLK=32. LDS 32KB: K fp8 dbuf 2x8KB + V fp8 dbuf 2x8KB. 2 blocks/CU.
// Counted-vmcnt 2-barrier pipeline: K waits before QK (V in flight), V waits before PV (next K in flight).
__global__ __launch_bounds__(256, 2) void k_attn(const u8* __restrict__ Q8,
                                                 const u8* __restrict__ K8,
                                                 const u8* __restrict__ V8,
                                                 u16* __restrict__ part,
                                                 float* __restrict__ ml) {
  __shared__ __attribute__((aligned(16))) char smem[32768];
  const int t = threadIdx.x;
  const int w = t >> 6, l = t & 63;
  const int q31 = l & 31, hi = l >> 5;
  const int head = blockIdx.x, qb = blockIdx.y, sp = blockIdx.z;
  const int kvbase = sp * 2048;
  const float C2 = 0.0625f * 1.44269504f;  // 1/sqrt(256) * log2(e)

  uint4 qf[8];
  {
    const u8* qp = Q8 + (size_t)(qb * 128 + w * 32 + q31) * 2048 + head * 256 + hi * 16;
#pragma unroll
    for (int g = 0; g < 8; ++g) qf[g] = *(const uint4*)(qp + g * 32);
  }

  f32x16 o[8] = {};
  float m = -1e30f, lsum = 0.0f;

  const u8* KbaseH = K8 + head * 256;
  const u8* VbaseH = V8 + (size_t)head * 1048576;

  auto stageK = [&](int cc) {
    char* kd = smem + (cc & 1) * 8192;
    const int kv0 = kvbase + cc * 32;
#pragma unroll
    for (int ii = 0; ii < 2; ++ii) {
      const int inst = w * 2 + ii;
      const int row = inst * 4 + (l >> 4);
      llds16(KbaseH + (size_t)(kv0 + row) * 2048 + ((l & 15) << 4), kd + inst * 1024);
    }
  };
  auto stageV = [&](int cc) {
    char* vd = smem + 16384 + (cc & 1) * 8192;
    const int kv0 = kvbase + cc * 32;
#pragma unroll
    for (int ii = 0; ii < 2; ++ii) {
      const int inst = w * 2 + ii;
      const int row = inst * 32 + (l >> 1);
      llds16(VbaseH + (size_t)row * 4096 + kv0 + ((l & 1) << 4), vd + inst * 1024);
    }
  };

  stageK(0);
  stageV(0);
  for (int c = 0; c < 64; ++c) {
    // --- K(c) ready; V(c) still in flight ---
    asm volatile("s_waitcnt vmcnt(2)" ::: "memory");
    __builtin_amdgcn_s_barrier();
    __builtin_amdgcn_sched_barrier(0);
    stageK((c + 1) & 63);

    const char* kd = smem + (c & 1) * 8192;
    const char* vd = smem + 16384 + (c & 1) * 8192;

    // S^T = K . Q^T : C[kv][q], fp8, two accumulator chains
    f32x16 sA = {}, sB = {};
    const char* ka = kd + q31 * 256;
    const int rsw = q31 & 15;
    __builtin_amdgcn_s_setprio(1);
#pragma unroll
    for (int g = 0; g < 8; ++g) {
      const int chunk = (g * 2 + hi) ^ rsw;
      uint4 kk = *(const uint4*)(ka + chunk * 16);
      long a0 = __builtin_bit_cast(long, (u32x2){ kk.x, kk.y });
      long a1 = __builtin_bit_cast(long, (u32x2){ kk.z, kk.w });
      long q0 = __builtin_bit_cast(long, (u32x2){ qf[g].x, qf[g].y });
      long q1 = __builtin_bit_cast(long, (u32x2){ qf[g].z, qf[g].w });
      sA = MFMA8(a0, q0, sA);
      sB = MFMA8(a1, q1, sB);
    }
    __builtin_amdgcn_s_setprio(0);
    f32x16 s = sA + sB;

    // online softmax (kv lane-local), tree reductions, defer-max
    float m8[8];
#pragma unroll
    for (int i = 0; i < 8; ++i) m8[i] = fmaxf(s[i], s[i + 8]);
#pragma unroll
    for (int i = 0; i < 4; ++i) m8[i] = fmaxf(m8[i], m8[i + 4]);
    float pm = fmaxf(fmaxf(m8[0], m8[1]), fmaxf(m8[2], m8[3]));
    pm = fmaxf(pm, __shfl_xor(pm, 32));
    if (__any(pm > m + 64.0f)) {
      float mn = fmaxf(m, pm);
      float sc = EXP2((m - mn) * C2);
      m = mn;
      lsum *= sc;
#pragma unroll
      for (int i = 0; i < 16; ++i) {
        const int r = (i & 3) + 8 * (i >> 2) + 4 * hi;
        float sclr = __shfl(sc, r);
#pragma unroll
        for (int dt = 0; dt < 8; ++dt) o[dt][i] *= sclr;
      }
    }
    const float mc2 = m * C2;
    float p[16];
#pragma unroll
    for (int i = 0; i < 16; ++i) p[i] = EXP2(fmaf(s[i], C2, -mc2));
    float r8[8];
#pragma unroll
    for (int i = 0; i < 8; ++i) r8[i] = p[i] + p[i + 8];
#pragma unroll
    for (int i = 0; i < 4; ++i) r8[i] += r8[i + 4];
    float rs = (r8[0] + r8[1]) + (r8[2] + r8[3]);
    rs += __shfl_xor(rs, 32);
    lsum += rs;

    // in-register P (fp8): pack 4x u32, 2 permlane swaps -> two 8B A-frags
    u32 pq0 = __builtin_amdgcn_cvt_pk_fp8_f32(p[0], p[1], 0, false);
    pq0 = __builtin_amdgcn_cvt_pk_fp8_f32(p[2], p[3], pq0, true);
    u32 pq1 = __builtin_amdgcn_cvt_pk_fp8_f32(p[4], p[5], 0, false);
    pq1 = __builtin_amdgcn_cvt_pk_fp8_f32(p[6], p[7], pq1, true);
    u32 pq2 = __builtin_amdgcn_cvt_pk_fp8_f32(p[8], p[9], 0, false);
    pq2 = __builtin_amdgcn_cvt_pk_fp8_f32(p[10], p[11], pq2, true);
    u32 pq3 = __builtin_amdgcn_cvt_pk_fp8_f32(p[12], p[13], 0, false);
    pq3 = __builtin_amdgcn_cvt_pk_fp8_f32(p[14], p[15], pq3, true);
    asm("v_permlane32_swap_b32 %0, %1" : "+v"(pq0), "+v"(pq1));
    asm("v_permlane32_swap_b32 %0, %1" : "+v"(pq2), "+v"(pq3));
    long paA = __builtin_bit_cast(long, (u32x2){ pq0, pq1 });
    long paB = __builtin_bit_cast(long, (u32x2){ pq2, pq3 });

    // --- V(c) ready; K(c+1) still in flight ---
    asm volatile("s_waitcnt vmcnt(2)" ::: "memory");
    __builtin_amdgcn_s_barrier();
    __builtin_amdgcn_sched_barrier(0);
    stageV((c + 1) & 63);

    // O += P . V : fp8 x fp8; one b128 per d-tile feeds both MFMA B-operands (kv-sigma layout)
    __builtin_amdgcn_s_setprio(1);
#pragma unroll
    for (int dt = 0; dt < 8; ++dt) {
      uint4 vv = *(const uint4*)(vd + (dt * 32 + q31) * 32 + hi * 16);
      long b0 = __builtin_bit_cast(long, (u32x2){ vv.x, vv.y });
      long b1 = __builtin_bit_cast(long, (u32x2){ vv.z, vv.w });
      o[dt] = MFMA8(paA, b0, o[dt]);
      o[dt] = MFMA8(paB, b1, o[dt]);
    }
    __builtin_amdgcn_s_setprio(0);
  }

  u16* pb = part + (size_t)sp * 4096 * 2048;
#pragma unroll
  for (int i = 0; i < 16; ++i) {
    const int r = (i & 3) + 8 * (i >> 2) + 4 * hi;
    const size_t qg = (size_t)(qb * 128 + w * 32 + r);
#pragma unroll
    for (int dt = 0; dt < 8; ++dt)
      pb[qg * 2048 + head * 256 + dt * 32 + q31] = f2b(o[dt][i]);
  }
  if (hi == 0) {
    const int qg = qb * 128 + w * 32 + q31;
    ml[((sp * 2 + 0) * 8 + head) * 4096 + qg] = m;
    ml[((sp * 2 + 1) * 8 + head) * 4096 + qg] = lsum;
  }
}

// ---------------- launch ----------------
extern "C" void kernel_launch(void* const* d_in, const int* in_sizes, int n_in,
                              void* d_out, int out_size, void* d_ws, size_t ws_size,
                              hipStream_t stream) {
  const float* x   = (const float*)d_in[0];
  const float* Wq  = (const float*)d_in[1];
  const float* Wk  = (const float*)d_in[2];
  const float* Wv  = (const float*)d_in[3];
  const float* Wo  = (const float*)d_in[4];
  const float* bo  = (const float*)d_in[5];
  const float* g1  = (const float*)d_in[6];
  const float* be1 = (const float*)d_in[7];
  const float* g2  = (const float*)d_in[8];
  const float* be2 = (const float*)d_in[9];
  const float* W1  = (const float*)d_in[10];
  const float* b1  = (const float*)d_in[11];
  const float* W2  = (const float*)d_in[12];
  const float* b2  = (const float*)d_in[13];

  char* ws = (char*)d_ws;
  size_t off = 0;
  auto alloc = [&](size_t n) {
    char* p = ws + off;
    off = (off + n + 255) & ~(size_t)255;
    return p;
  };
  u16* hb    = (u16*)alloc(4096 * 256 * 2);
  u16* Wqb   = (u16*)alloc(2048 * 256 * 2);
  u16* Wkb   = (u16*)alloc(2048 * 256 * 2);
  u16* Wvb   = (u16*)alloc(2048 * 256 * 2);
  u16* Wob   = (u16*)alloc(256 * 2048 * 2);
  u16* W1b   = (u16*)alloc(1024 * 256 * 2);
  u16* W2b   = (u16*)alloc(256 * 1024 * 2);
  u8*  Qb8   = (u8*)alloc((size_t)4096 * 2048);      // fp8 sigma-d layout
  u8*  Kb8   = (u8*)alloc((size_t)4096 * 2048);      // fp8 sigma-d layout, row-swizzled
  u8*  Vb8   = (u8*)alloc((size_t)2048 * 4096);      // fp8 [head][d][kv_sigma]
  u16* attnb = (u16*)alloc((size_t)2 * 4096 * 2048 * 2);  // 2 kv-split partials (merged in Wo GEMM)
  float* mlb = (float*)alloc(32 * 4096 * 4);
  float* x2  = (float*)alloc(4096 * 256 * 4);
  u16* h2b   = (u16*)alloc(4096 * 256 * 2);
  u16* ffn1  = (u16*)alloc((size_t)4096 * 1024 * 2);
  float* pbuf = (float*)Qb8;  // Qb8+Kb8 = 16MB contiguous, dead after k_attn: 4x [4096][256] f32

  k_prep<<<dim3(1024, 7), 256, 0, stream>>>(Wq, Wk, Wv, Wo, W1, W2,
                                            Wqb, Wkb, Wvb, Wob, W1b, W2b,
                                            x, g1, be1, hb);

  k_gemm_qkv<<<dim3(48, 32), 256, 0, stream>>>(hb, Wqb, Wkb, Wvb, Qb8, Kb8, Vb8);

  k_attn<<<dim3(8, 32, 2), 256, 0, stream>>>(Qb8, Kb8, Vb8, attnb, mlb);

  k_gemm_wo<<<dim3(2, 32, 4), 256, 0, stream>>>(attnb, mlb, Wob, pbuf);
  k_red4ln<<<1024, 256, 0, stream>>>(pbuf, bo, x, g2, be2, x2, h2b);
  k_gemm<3><<<dim3(8, 32), 256, 0, stream>>>(h2b, W1b, ffn1, b1, 4096, 1024, 256);
  k_gemm<4><<<dim3(2, 32, 4), 256, 0, stream>>>(ffn1, W2b, pbuf, nullptr, 4096, 256, 1024);
  k_red4<<<1024, 256, 0, stream>>>(pbuf, b2, x2, (float*)d_out);
}